// Round 11
// baseline (208.584 us; speedup 1.0000x reference)
//
#include <hip/hip_runtime.h>

#define NB   2
#define NHD  8
#define BH   16
#define HD   16
#define N0   9216
#define N1   2304
#define N2   576
#define W0_  96
#define W1_  48
#define W2_  24
#define M_TOT 18432
#define TEMP 0.25f

// exact k-th largest of the 64 per-lane values v (multiset semantics, duplicates counted).
// 2-bit-radix MSB-first ballot search on an order-isomorphic uint mapping: per step the
// three candidate ballots depend only on the previous g (not on each other), so the
// dependent chain is 16 steps instead of 32. Greedy MSB-first over 2-bit digits returns
// the exact k-th largest (same greedy invariant as 1-bit) -> result bit-identical.
__device__ __forceinline__ float kth_largest64(float v, int k){
    unsigned b = __float_as_uint(v);
    unsigned u = (b & 0x80000000u) ? ~b : (b | 0x80000000u);
    unsigned g = 0u;
#pragma unroll
    for(int p=30; p>=0; p-=2){
        unsigned c1 = g | (1u<<p);
        unsigned c2 = g | (2u<<p);
        unsigned c3 = g | (3u<<p);
        int n1 = (int)__popcll(__ballot(u >= c1));
        int n2 = (int)__popcll(__ballot(u >= c2));
        int n3 = (int)__popcll(__ballot(u >= c3));
        g = (n3 >= k) ? c3 : ((n2 >= k) ? c2 : ((n1 >= k) ? c1 : g));
    }
    unsigned rb = (g & 0x80000000u) ? (g & 0x7FFFFFFFu) : ~g;
    return __uint_as_float(rb);
}

// integer-exact exclusive wave scan of small counts (ci <= 15) via 4 ballots + mbcnt;
// replaces a 6-step dependent __shfl_up chain. Also returns the wave total C.
__device__ __forceinline__ void scan_counts64(int ci, int &excl, int &C){
    excl = 0; C = 0;
#pragma unroll
    for(int b=0;b<4;b++){
        unsigned long long mb = __ballot(((unsigned)ci>>b)&1u);
        int lt = __builtin_amdgcn_mbcnt_lo((unsigned)mb, 0);
        lt = __builtin_amdgcn_mbcnt_hi((unsigned)(mb>>32), lt);
        excl += lt << b;
        C += ((int)__popcll(mb)) << b;
    }
}

// ---------------- projection GEMM: dst[(b,h,n,d)] = sum_c A[m][c] * W[o][c] ----------------
// 64x128 tile (verified layout); staging loads for the next K-slab are issued right after the
// first barrier so they hide under the 16-kk math. FMA order bit-identical.
__global__ __launch_bounds__(256) void k_proj(const float* __restrict__ x, const float* __restrict__ tg,
    const float* __restrict__ Wq, const float* __restrict__ Wk, const float* __restrict__ Wv,
    float* __restrict__ q0, float* __restrict__ k0, float* __restrict__ v0)
{
    __shared__ __align__(16) float At[16][68];   // [k][row]
    __shared__ __align__(16) float Wt[16][132];  // [k][o]
    const int t = threadIdx.x;
    const int which = blockIdx.y;
    const float* A  = (which==0)? x : tg;
    const float* Wm = (which==0)? Wq : (which==1? Wk : Wv);
    float* dst      = (which==0)? q0 : (which==1? k0 : v0);
    const int m0 = blockIdx.x * 64;
    const int tx = t & 15, ty = t >> 4;

    float acc[4][8];
#pragma unroll
    for(int i=0;i<4;i++)
#pragma unroll
        for(int j=0;j<8;j++) acc[i][j]=0.f;

    const int ar = t>>2, akq = (t&3)*4;
    const int wo = t>>1, wkq = (t&1)*8;

    float4 av = *(const float4*)(A + (m0+ar)*128 + akq);
    float4 w0 = *(const float4*)(Wm + wo*128 + wkq);
    float4 w1 = *(const float4*)(Wm + wo*128 + wkq + 4);

    for(int kc=0;kc<128;kc+=16){
        At[akq+0][ar] = av.x;
        At[akq+1][ar] = av.y;
        At[akq+2][ar] = av.z;
        At[akq+3][ar] = av.w;
        Wt[wkq+0][wo] = w0.x; Wt[wkq+1][wo] = w0.y;
        Wt[wkq+2][wo] = w0.z; Wt[wkq+3][wo] = w0.w;
        Wt[wkq+4][wo] = w1.x; Wt[wkq+5][wo] = w1.y;
        Wt[wkq+6][wo] = w1.z; Wt[wkq+7][wo] = w1.w;
        __syncthreads();
        float4 nav, nw0, nw1;
        if (kc < 112){   // issue next slab's loads; they complete under the kk math
            nav = *(const float4*)(A + (m0+ar)*128 + kc+16 + akq);
            nw0 = *(const float4*)(Wm + wo*128 + kc+16 + wkq);
            nw1 = *(const float4*)(Wm + wo*128 + kc+16 + wkq + 4);
        }
#pragma unroll
        for(int kk=0;kk<16;kk++){
            float4 a4 = *(const float4*)&At[kk][ty*4];
            float4 wa = *(const float4*)&Wt[kk][tx*4];
            float4 wb = *(const float4*)&Wt[kk][64 + tx*4];
            float avr[4] = {a4.x,a4.y,a4.z,a4.w};
            float wvr[8] = {wa.x,wa.y,wa.z,wa.w, wb.x,wb.y,wb.z,wb.w};
#pragma unroll
            for(int i=0;i<4;i++)
#pragma unroll
                for(int j=0;j<8;j++) acc[i][j] += avr[i]*wvr[j];
        }
        __syncthreads();
        if (kc < 112){ av = nav; w0 = nw0; w1 = nw1; }
    }
    const int hA = tx>>2, dA = (tx&3)*4;
#pragma unroll
    for(int i=0;i<4;i++){
        int m = m0 + ty*4 + i;
        int b = m / N0; int n = m - b*N0;
        float4 sA = make_float4(acc[i][0], acc[i][1], acc[i][2], acc[i][3]);
        float4 sB = make_float4(acc[i][4], acc[i][5], acc[i][6], acc[i][7]);
        *(float4*)(dst + ((b*NHD + hA    )*N0 + n)*16 + dA) = sA;
        *(float4*)(dst + ((b*NHD + hA + 4)*N0 + n)*16 + dA) = sB;
    }
}

// ---- FUSED pooling: level0 -> level1 (row layout) AND level1 -> level2 (q row, k/v transposed) ----
__global__ __launch_bounds__(256) void k_pool01(const float4* __restrict__ src0,
    float4* __restrict__ dst1, float4* __restrict__ q2f,
    float4* __restrict__ k2T, float4* __restrict__ v2T)
{
    int tid = blockIdx.x*256 + threadIdx.x;
    if (tid >= 110592) return;
    int d4 = tid & 3;
    int rest = tid >> 2;
    int n2 = rest % N2; int g = rest / N2;     // g in [0,48): 0-15 q, 16-31 k, 32-47 v
    int yo2 = n2 / W2_, xo2 = n2 - yo2*W2_;

    const float4* s = src0 + g*N0*4;
    float4* d1 = dst1 + g*N1*4;
    float4 l1[4];
#pragma unroll
    for(int yy=0;yy<2;yy++){
#pragma unroll
        for(int xx=0;xx<2;xx++){
            int y1 = 2*yo2+yy, x1 = 2*xo2+xx;
            int n1 = y1*W1_ + x1;
            int cbase = (2*y1)*W0_ + 2*x1;
            float4 a = s[(cbase       )*4 + d4];
            float4 b = s[(cbase+1     )*4 + d4];
            float4 c = s[(cbase+W0_   )*4 + d4];
            float4 d = s[(cbase+W0_+1 )*4 + d4];
            float4 o;
            o.x = 0.25f*(a.x+b.x+c.x+d.x);
            o.y = 0.25f*(a.y+b.y+c.y+d.y);
            o.z = 0.25f*(a.z+b.z+c.z+d.z);
            o.w = 0.25f*(a.w+b.w+c.w+d.w);
            d1[n1*4 + d4] = o;
            l1[yy*2+xx] = o;
        }
    }
    float4 o2;
    o2.x = 0.25f*(l1[0].x+l1[1].x+l1[2].x+l1[3].x);
    o2.y = 0.25f*(l1[0].y+l1[1].y+l1[2].y+l1[3].y);
    o2.z = 0.25f*(l1[0].z+l1[1].z+l1[2].z+l1[3].z);
    o2.w = 0.25f*(l1[0].w+l1[1].w+l1[2].w+l1[3].w);
    int grp = g >> 4, bh = g & 15;
    if (grp == 0)      q2f[(bh*N2 + n2)*4 + d4] = o2;
    else if (grp == 1) k2T[(bh*4 + d4)*N2 + n2] = o2;
    else               v2T[(bh*4 + d4)*N2 + n2] = o2;
}

// threshold-pruned exact top-16 of 576 exp-values (9 per lane), tie-break smaller global index.
__device__ __forceinline__ void top16_sel(const float ev[9], int lane, float* cv, int* cx, int* ip)
{
    // 1. per-lane head
    float head = ev[0];
#pragma unroll
    for(int i=1;i<9;i++) head = fmaxf(head, ev[i]);

    // 2. T = exact 16th-largest head (ballot radix search)
    float T = kth_largest64(head, 16);   // >=16 values are >= T -> top-16 subset of candidates

    // 3. per-lane candidate count + ballot-based exclusive scan (integer-exact)
    int ci = 0;
#pragma unroll
    for(int i=0;i<9;i++) ci += (ev[i] >= T) ? 1 : 0;
    int excl, C;
    scan_counts64(ci, excl, C);          // C >= 16 guaranteed

    // 4. deposit candidates into this wave's LDS region; pad 4 sentinels
    int o = excl;
#pragma unroll
    for(int i=0;i<9;i++){
        if (ev[i] >= T){
            cv[o] = ev[i];
            cx[o] = i*64 + lane;
            o++;
        }
    }
    if (lane < 4){ cv[C+lane] = -1.0f; cx[C+lane] = 0x7fffffff; }
    // in-wave DS ordering: reads below are same-wave, issued after the writes

    // 5. rank each candidate against all candidates (broadcast float4 scans)
    for(int l=lane; l<C; l+=64){
        float mv = cv[l]; int mi = cx[l];
        int rank = 0;
        for(int c=0;c<C;c+=4){
            float4 vv = *(const float4*)(cv + c);
            int4   ii = *(const int4*)(cx + c);
            rank += (vv.x > mv || (vv.x == mv && ii.x < mi)) ? 1 : 0;
            rank += (vv.y > mv || (vv.y == mv && ii.y < mi)) ? 1 : 0;
            rank += (vv.z > mv || (vv.z == mv && ii.z < mi)) ? 1 : 0;
            rank += (vv.w > mv || (vv.w == mv && ii.w < mi)) ? 1 : 0;
        }
        if (rank < 16) ip[rank] = mi;
    }
}

// register ping-pong staging (round-4 verified schedule): scheduling-only, arithmetic
// identical to the two-pass max-shift version -> selection values unchanged.
#define LOADK(KB, T9) { int m_=(T9)*64+lane; \
    KB[0]=kT[0*N2+m_]; KB[1]=kT[1*N2+m_]; KB[2]=kT[2*N2+m_]; KB[3]=kT[3*N2+m_]; }
#define LOADV(VB, T9) { int m_=(T9)*64+lane; \
    VB[0]=vT[0*N2+m_]; VB[1]=vT[1*N2+m_]; VB[2]=vT[2*N2+m_]; VB[3]=vT[3*N2+m_]; }
#define STEPK(T9, KB) { float sA=0.f, sB=0.f; \
    _Pragma("unroll") \
    for(int dg=0;dg<4;dg++){ float4 kv=KB[dg]; \
      sA += qrA[dg*4+0]*kv.x + qrA[dg*4+1]*kv.y + qrA[dg*4+2]*kv.z + qrA[dg*4+3]*kv.w; \
      sB += qrB[dg*4+0]*kv.x + qrB[dg*4+1]*kv.y + qrB[dg*4+2]*kv.z + qrB[dg*4+3]*kv.w; } \
    sA *= TEMP; sB *= TEMP; \
    evA[T9]=sA; evB[T9]=sB; \
    mxA = fmaxf(mxA, sA); mxB = fmaxf(mxB, sB); }
#define STEPV(T9, VB) { \
    float eA=expf(evA[T9]-mxA), eB=expf(evB[T9]-mxB); \
    evA[T9]=eA; evB[T9]=eB; sumA+=eA; sumB+=eB; \
    _Pragma("unroll") \
    for(int dg=0;dg<4;dg++){ float4 vv=VB[dg]; \
      accA[dg*4+0]+=eA*vv.x; accA[dg*4+1]+=eA*vv.y; accA[dg*4+2]+=eA*vv.z; accA[dg*4+3]+=eA*vv.w; \
      accB[dg*4+0]+=eB*vv.x; accB[dg*4+1]+=eB*vv.y; accB[dg*4+2]+=eB*vv.z; accB[dg*4+3]+=eB*vv.w; } }

// ---- level-2 full attention + top-16: 2 queries/wave, two passes with max-shift, register
// ping-pong double-buffer per pass (k loads overlap score FMAs; v loads overlap exp+PV). ----
__global__ __launch_bounds__(256) void k_attn2(const float* __restrict__ q2, const float* __restrict__ k2,
    const float* __restrict__ v2, float* __restrict__ msg2, int* __restrict__ idx2)
{
    __shared__ __align__(16) float cval[4][580];
    __shared__ __align__(16) int   cidx[4][580];
    const int bh = blockIdx.x;
    const int wv = threadIdx.x>>6, lane = threadIdx.x&63;
    const int qA = blockIdx.y*8 + wv*2;   // two queries per wave
    const int qB = qA + 1;

    float qrA[16], qrB[16];
    {
        const float4* qpA = (const float4*)(q2 + (bh*N2 + qA)*16);
        const float4* qpB = (const float4*)(q2 + (bh*N2 + qB)*16);
#pragma unroll
        for(int dq=0;dq<4;dq++){
            float4 va = qpA[dq];
            qrA[dq*4+0]=va.x; qrA[dq*4+1]=va.y; qrA[dq*4+2]=va.z; qrA[dq*4+3]=va.w;
            float4 vb = qpB[dq];
            qrB[dq*4+0]=vb.x; qrB[dq*4+1]=vb.y; qrB[dq*4+2]=vb.z; qrB[dq*4+3]=vb.w;
        }
    }

    const float4* kT = (const float4*)k2 + bh*4*N2;   // [dg][m]
    const float4* vT = (const float4*)v2 + bh*4*N2;

    // ---- pass 1: scores + running max (k ping-pong) ----
    float evA[9], evB[9];
    float mxA = -1e30f, mxB = -1e30f;
    {
        float4 ka[4], kb[4];
        LOADK(ka, 0);
#pragma unroll
        for(int t2=0;t2<4;t2++){
            LOADK(kb, 2*t2+1);
            STEPK(2*t2, ka);
            LOADK(ka, 2*t2+2);
            STEPK(2*t2+1, kb);
        }
        STEPK(8, ka);
    }
#pragma unroll
    for(int st=1; st<64; st<<=1){
        mxA = fmaxf(mxA, __shfl_xor(mxA, st));
        mxB = fmaxf(mxB, __shfl_xor(mxB, st));
    }

    // ---- pass 2: exp + PV accumulate (v ping-pong) ----
    float sumA=0.f, sumB=0.f;
    float accA[16], accB[16];
#pragma unroll
    for(int d=0;d<16;d++){ accA[d]=0.f; accB[d]=0.f; }
    {
        float4 va_[4], vb[4];
        LOADV(va_, 0);
#pragma unroll
        for(int t2=0;t2<4;t2++){
            LOADV(vb, 2*t2+1);
            STEPV(2*t2, va_);
            LOADV(va_, 2*t2+2);
            STEPV(2*t2+1, vb);
        }
        STEPV(8, va_);
    }
#pragma unroll
    for(int st=1; st<64; st<<=1){
        sumA += __shfl_xor(sumA, st);
        sumB += __shfl_xor(sumB, st);
    }

    // ---- tree-reduce 16-dim accumulators over 64 lanes, A and B interleaved ----
    const bool b5 = (lane & 32) != 0;
    const bool b4 = (lane & 16) != 0;
    const bool b3 = (lane & 8) != 0;
    const bool b2 = (lane & 4) != 0;
    float r8A[8], r8B[8];
#pragma unroll
    for(int i=0;i<8;i++){
        float sndA  = b5 ? accA[i]   : accA[i+8];
        float keptA = b5 ? accA[i+8] : accA[i];
        r8A[i] = keptA + __shfl_xor(sndA, 32);
        float sndB  = b5 ? accB[i]   : accB[i+8];
        float keptB = b5 ? accB[i+8] : accB[i];
        r8B[i] = keptB + __shfl_xor(sndB, 32);
    }
    float r4A[4], r4B[4];
#pragma unroll
    for(int i=0;i<4;i++){
        float sndA  = b4 ? r8A[i]   : r8A[i+4];
        float keptA = b4 ? r8A[i+4] : r8A[i];
        r4A[i] = keptA + __shfl_xor(sndA, 16);
        float sndB  = b4 ? r8B[i]   : r8B[i+4];
        float keptB = b4 ? r8B[i+4] : r8B[i];
        r4B[i] = keptB + __shfl_xor(sndB, 16);
    }
    float r2A[2], r2B[2];
#pragma unroll
    for(int i=0;i<2;i++){
        float sndA  = b3 ? r4A[i]   : r4A[i+2];
        float keptA = b3 ? r4A[i+2] : r4A[i];
        r2A[i] = keptA + __shfl_xor(sndA, 8);
        float sndB  = b3 ? r4B[i]   : r4B[i+2];
        float keptB = b3 ? r4B[i+2] : r4B[i];
        r2B[i] = keptB + __shfl_xor(sndB, 8);
    }
    {
        float sndA  = b2 ? r2A[0] : r2A[1];
        float keptA = b2 ? r2A[1] : r2A[0];
        r2A[0] = keptA + __shfl_xor(sndA, 4);
        float sndB  = b2 ? r2B[0] : r2B[1];
        float keptB = b2 ? r2B[1] : r2B[0];
        r2B[0] = keptB + __shfl_xor(sndB, 4);
    }
    r2A[0] += __shfl_xor(r2A[0], 2);
    r2B[0] += __shfl_xor(r2B[0], 2);
    r2A[0] += __shfl_xor(r2A[0], 1);
    r2B[0] += __shfl_xor(r2B[0], 1);
    float invA = 1.0f/sumA, invB = 1.0f/sumB;
    if ((lane&3)==0){
        msg2[(bh*N2+qA)*16 + (lane>>2)] = r2A[0]*invA;
        msg2[(bh*N2+qB)*16 + (lane>>2)] = r2B[0]*invB;
    }

    // ---- top-16 for both queries (sequential reuse of per-wave LDS region) ----
    top16_sel(evA, lane, cval[wv], cidx[wv], idx2 + (bh*N2+qA)*16);
    top16_sel(evB, lane, cval[wv], cidx[wv], idx2 + (bh*N2+qB)*16);
}

// ---- FUSED refinement: wave owns 1 parent + its 4 children; TWO tiles per block
// (sequential, wave-private LDS slots reused in-order -> no barrier, outputs identical).
// Selection ranks on raw s (kth ballot), so __expf (message values only) is safe here.
__global__ __launch_bounds__(256) void k_ref10(
    const float* __restrict__ q1, const float* __restrict__ k1, const float* __restrict__ v1,
    const float* __restrict__ q0, const float* __restrict__ k0, const float* __restrict__ v0,
    const float* __restrict__ msg2, const int* __restrict__ idx2, float* __restrict__ msg0)
{
    __shared__ float msg1s[4][16];
    __shared__ int   idx1s[4][8];
    // XCD swizzle: 4608 blocks = 8 x 576; each block owns 2 consecutive original tiles
    // (pairs (2b,2b+1) never cross a bh boundary since 576 is even).
    const int bid2 = (blockIdx.x & 7)*576 + (blockIdx.x >> 3);
    const int wv = threadIdx.x>>6, lane = threadIdx.x&63;

#pragma unroll 1
    for(int sub_t=0; sub_t<2; ++sub_t){
        const int bid = bid2*2 + sub_t;
        const int bh = bid / 576, tile = bid - bh*576;
        const int tyy = tile / 24, txx = tile - tyy*24;
        const int py0 = tyy*2, px0 = txx*2;      // 2x2 parent tile origin (level-1 coords)
        const int ppy = py0 + (wv>>1), ppx = px0 + (wv&1);   // this wave's parent (level-1)

        // ---------- phase 1: ref1 for parent wv ----------
        {
            const int n  = ppy*W1_ + ppx;
            const int par = (ppy>>1)*W2_ + (ppx>>1);
            const int kk = lane>>2, tt = lane&3, dy = tt>>1, dx = tt&1;
            int p = idx2[(bh*N2+par)*16 + kk];
            int ky = p / W2_, kx = p - ky*W2_;
            int child = (2*ky+dy)*W1_ + 2*kx+dx;

            const float* qp = q1 + (bh*N1+n)*16;
            float qr[16];
#pragma unroll
            for(int d=0; d<16; d+=4){
                float4 qq = *(const float4*)(qp+d);
                qr[d]=qq.x; qr[d+1]=qq.y; qr[d+2]=qq.z; qr[d+3]=qq.w;
            }
            const float4* kp = (const float4*)(k1 + (bh*N1+child)*16);
            float s = 0.f;
#pragma unroll
            for(int dq=0;dq<4;dq++){
                float4 kv = kp[dq];
                s += qr[dq*4+0]*kv.x + qr[dq*4+1]*kv.y + qr[dq*4+2]*kv.z + qr[dq*4+3]*kv.w;
            }
            s *= TEMP;

            // top-8 SET selection hoisted before the softmax reduction (VALU/SALU chain
            // overlaps the DS-pipe shuffle trees below).
            float T8 = kth_largest64(s, 8);
            unsigned long long mgt = __ballot(s > T8);
            unsigned long long meq = __ballot(s == T8);
            int ngt = (int)__popcll(mgt);
            int ltg = __builtin_amdgcn_mbcnt_lo((unsigned)mgt, 0);
            ltg = __builtin_amdgcn_mbcnt_hi((unsigned)(mgt>>32), ltg);
            int lte = __builtin_amdgcn_mbcnt_lo((unsigned)meq, 0);
            lte = __builtin_amdgcn_mbcnt_hi((unsigned)(meq>>32), lte);
            int slot = (s > T8) ? ltg : ((s == T8) ? (ngt + lte) : 8);
            if (slot < 8) idx1s[wv][slot] = child;

            float e = __expf(s);
            float sum = e;
#pragma unroll
            for(int st=1; st<64; st<<=1) sum += __shfl_xor(sum, st);

            float acc[16];
            const float4* vp = (const float4*)(v1 + (bh*N1+child)*16);
#pragma unroll
            for(int dq=0;dq<4;dq++){
                float4 vv = vp[dq];
                acc[dq*4+0]=e*vv.x; acc[dq*4+1]=e*vv.y; acc[dq*4+2]=e*vv.z; acc[dq*4+3]=e*vv.w;
            }
            const bool b5 = (lane & 32) != 0;
            float r8[8];
#pragma unroll
            for(int ii=0;ii<8;ii++){
                float snd  = b5 ? acc[ii]   : acc[ii+8];
                float kept = b5 ? acc[ii+8] : acc[ii];
                r8[ii] = kept + __shfl_xor(snd, 32);
            }
            const bool b4 = (lane & 16) != 0;
            float r4[4];
#pragma unroll
            for(int ii=0;ii<4;ii++){
                float snd  = b4 ? r8[ii]   : r8[ii+4];
                float kept = b4 ? r8[ii+4] : r8[ii];
                r4[ii] = kept + __shfl_xor(snd, 16);
            }
            const bool b3 = (lane & 8) != 0;
            float r2[2];
#pragma unroll
            for(int ii=0;ii<2;ii++){
                float snd  = b3 ? r4[ii]   : r4[ii+2];
                float kept = b3 ? r4[ii+2] : r4[ii];
                r2[ii] = kept + __shfl_xor(snd, 8);
            }
            const bool b2 = (lane & 4) != 0;
            {
                float snd  = b2 ? r2[0] : r2[1];
                float kept = b2 ? r2[1] : r2[0];
                r2[0] = kept + __shfl_xor(snd, 4);
            }
            r2[0] += __shfl_xor(r2[0], 2);
            r2[0] += __shfl_xor(r2[0], 1);

            float inv1 = 1.0f/sum;
            if ((lane&3)==0){
                int d = lane>>2;
                msg1s[wv][d] = msg2[(bh*N2+par)*16 + d] + r2[0]*inv1;
            }
        }
        // no __syncthreads: each wave reads only its own msg1s[wv]/idx1s[wv] (in-wave DS order)

        // ---------- phase 2: this parent's 4 children; both query-iterations interleaved ----------
        const int j = lane & 31, sub = lane >> 5;
        const int kk = j>>2, tt = j&3, dy = tt>>1, dx = tt&1;
        int p = idx1s[wv][kk];
        int ky = p / W1_, kx = p - ky*W1_;
        int child = (2*ky+dy)*W0_ + 2*kx+dx;

        float kr[16];
        {
            const float4* kp = (const float4*)(k0 + (bh*N0+child)*16);
#pragma unroll
            for(int dq=0;dq<4;dq++){
                float4 kv = kp[dq];
                kr[dq*4+0]=kv.x; kr[dq*4+1]=kv.y; kr[dq*4+2]=kv.z; kr[dq*4+3]=kv.w;
            }
        }
        const int cy0 = 2*ppy, cx0 = 2*ppx + sub;
        int nq[2];
        float s_[2];
#pragma unroll
        for(int it=0; it<2; it++){
            nq[it] = (cy0+it)*W0_ + cx0;
            const float* qp = q0 + (bh*N0+nq[it])*16;
            float qr[16];
#pragma unroll
            for(int d=0; d<16; d+=4){
                float4 qq = *(const float4*)(qp+d);
                qr[d]=qq.x; qr[d+1]=qq.y; qr[d+2]=qq.z; qr[d+3]=qq.w;
            }
            float s = 0.f;
#pragma unroll
            for(int dq=0;dq<4;dq++){
                s += qr[dq*4+0]*kr[dq*4+0] + qr[dq*4+1]*kr[dq*4+1]
                   + qr[dq*4+2]*kr[dq*4+2] + qr[dq*4+3]*kr[dq*4+3];
            }
            s_[it] = s * TEMP;
        }
        float vr[16];
        {
            const float4* vp = (const float4*)(v0 + (bh*N0+child)*16);
#pragma unroll
            for(int dq=0;dq<4;dq++){
                float4 vv = vp[dq];
                vr[dq*4+0]=vv.x; vr[dq*4+1]=vv.y; vr[dq*4+2]=vv.z; vr[dq*4+3]=vv.w;
            }
        }
        const float m1d = msg1s[wv][j>>1];

        float e0 = __expf(s_[0]);
        float e1 = __expf(s_[1]);
        float sum0 = e0, sum1 = e1;
#pragma unroll
        for(int st=1; st<32; st<<=1){
            sum0 += __shfl_xor(sum0, st);
            sum1 += __shfl_xor(sum1, st);
        }

        float acc0[16], acc1[16];
#pragma unroll
        for(int d=0;d<16;d++){ acc0[d] = e0*vr[d]; acc1[d] = e1*vr[d]; }

        const bool c4 = (j & 16) != 0;
        float p8A[8], p8B[8];
#pragma unroll
        for(int ii=0;ii<8;ii++){
            float sndA  = c4 ? acc0[ii]   : acc0[ii+8];
            float keptA = c4 ? acc0[ii+8] : acc0[ii];
            p8A[ii] = keptA + __shfl_xor(sndA, 16);
            float sndB  = c4 ? acc1[ii]   : acc1[ii+8];
            float keptB = c4 ? acc1[ii+8] : acc1[ii];
            p8B[ii] = keptB + __shfl_xor(sndB, 16);
        }
        const bool c3 = (j & 8) != 0;
        float p4A[4], p4B[4];
#pragma unroll
        for(int ii=0;ii<4;ii++){
            float sndA  = c3 ? p8A[ii]   : p8A[ii+4];
            float keptA = c3 ? p8A[ii+4] : p8A[ii];
            p4A[ii] = keptA + __shfl_xor(sndA, 8);
            float sndB  = c3 ? p8B[ii]   : p8B[ii+4];
            float keptB = c3 ? p8B[ii+4] : p8B[ii];
            p4B[ii] = keptB + __shfl_xor(sndB, 8);
        }
        const bool c2 = (j & 4) != 0;
        float p2A[2], p2B[2];
#pragma unroll
        for(int ii=0;ii<2;ii++){
            float sndA  = c2 ? p4A[ii]   : p4A[ii+2];
            float keptA = c2 ? p4A[ii+2] : p4A[ii];
            p2A[ii] = keptA + __shfl_xor(sndA, 4);
            float sndB  = c2 ? p4B[ii]   : p4B[ii+2];
            float keptB = c2 ? p4B[ii+2] : p4B[ii];
            p2B[ii] = keptB + __shfl_xor(sndB, 4);
        }
        const bool c1 = (j & 2) != 0;
        {
            float sndA  = c1 ? p2A[0] : p2A[1];
            float keptA = c1 ? p2A[1] : p2A[0];
            p2A[0] = keptA + __shfl_xor(sndA, 2);
            float sndB  = c1 ? p2B[0] : p2B[1];
            float keptB = c1 ? p2B[1] : p2B[0];
            p2B[0] = keptB + __shfl_xor(sndB, 2);
        }
        p2A[0] += __shfl_xor(p2A[0], 1);
        p2B[0] += __shfl_xor(p2B[0], 1);

        float inv0 = 1.0f/sum0, inv1 = 1.0f/sum1;
        if ((j&1)==0){
            int d = j>>1;
            int b_ = bh>>3, h = bh&7;
            msg0[(b_*N0+nq[0])*128 + h*16 + d] = m1d + p2A[0]*inv0;
            msg0[(b_*N0+nq[1])*128 + h*16 + d] = m1d + p2B[0]*inv1;
        }
    }
}

// ---------------- output projection GEMM + bias (same staging prefetch as k_proj) ----------------
__global__ __launch_bounds__(256) void k_out(const float* __restrict__ msg0, const float* __restrict__ Wo,
    const float* __restrict__ bo, float* __restrict__ out)
{
    __shared__ __align__(16) float At[16][68];
    __shared__ __align__(16) float Wt[16][132];
    const int t = threadIdx.x;
    const int m0 = blockIdx.x * 64;
    const int tx = t & 15, ty = t >> 4;

    float acc[4][8];
#pragma unroll
    for(int i=0;i<4;i++)
#pragma unroll
        for(int j=0;j<8;j++) acc[i][j]=0.f;

    const int ar = t>>2, akq = (t&3)*4;
    const int wo = t>>1, wkq = (t&1)*8;

    float4 av = *(const float4*)(msg0 + (m0+ar)*128 + akq);
    float4 w0 = *(const float4*)(Wo + wo*128 + wkq);
    float4 w1 = *(const float4*)(Wo + wo*128 + wkq + 4);

    for(int kc=0;kc<128;kc+=16){
        At[akq+0][ar] = av.x;
        At[akq+1][ar] = av.y;
        At[akq+2][ar] = av.z;
        At[akq+3][ar] = av.w;
        Wt[wkq+0][wo] = w0.x; Wt[wkq+1][wo] = w0.y;
        Wt[wkq+2][wo] = w0.z; Wt[wkq+3][wo] = w0.w;
        Wt[wkq+4][wo] = w1.x; Wt[wkq+5][wo] = w1.y;
        Wt[wkq+6][wo] = w1.z; Wt[wkq+7][wo] = w1.w;
        __syncthreads();
        float4 nav, nw0, nw1;
        if (kc < 112){
            nav = *(const float4*)(msg0 + (m0+ar)*128 + kc+16 + akq);
            nw0 = *(const float4*)(Wo + wo*128 + kc+16 + wkq);
            nw1 = *(const float4*)(Wo + wo*128 + kc+16 + wkq + 4);
        }
#pragma unroll
        for(int kk=0;kk<16;kk++){
            float4 a4 = *(const float4*)&At[kk][ty*4];
            float4 wa = *(const float4*)&Wt[kk][tx*4];
            float4 wb = *(const float4*)&Wt[kk][64 + tx*4];
            float avr[4] = {a4.x,a4.y,a4.z,a4.w};
            float wvr[8] = {wa.x,wa.y,wa.z,wa.w, wb.x,wb.y,wb.z,wb.w};
#pragma unroll
            for(int i=0;i<4;i++)
#pragma unroll
                for(int j=0;j<8;j++) acc[i][j] += avr[i]*wvr[j];
        }
        __syncthreads();
        if (kc < 112){ av = nav; w0 = nw0; w1 = nw1; }
    }
#pragma unroll
    for(int i=0;i<4;i++){
        int m = m0 + ty*4 + i;
        float4 sA = make_float4(acc[i][0]+bo[tx*4+0], acc[i][1]+bo[tx*4+1],
                                acc[i][2]+bo[tx*4+2], acc[i][3]+bo[tx*4+3]);
        float4 sB = make_float4(acc[i][4]+bo[64+tx*4+0], acc[i][5]+bo[64+tx*4+1],
                                acc[i][6]+bo[64+tx*4+2], acc[i][7]+bo[64+tx*4+3]);
        *(float4*)(out + m*128 + tx*4)      = sA;
        *(float4*)(out + m*128 + 64 + tx*4) = sB;
    }
}

extern "C" void kernel_launch(void* const* d_in, const int* in_sizes, int n_in,
                              void* d_out, int out_size, void* d_ws, size_t ws_size,
                              hipStream_t stream) {
    const float* x  = (const float*)d_in[0];
    const float* tg = (const float*)d_in[1];
    const float* Wq = (const float*)d_in[2];
    const float* Wk = (const float*)d_in[3];
    const float* Wv = (const float*)d_in[4];
    const float* Wo = (const float*)d_in[5];
    const float* bo = (const float*)d_in[6];

    float* ws = (float*)d_ws;
    float* q0   = ws + 0;
    float* k0   = ws + 2359296;
    float* v0   = ws + 4718592;
    float* q1   = ws + 7077888;
    float* k1   = ws + 7667712;
    float* v1   = ws + 8257536;
    float* q2   = ws + 8847360;
    float* k2   = ws + 8994816;   // k2T [bh][dg][m] float4
    float* v2   = ws + 9142272;   // v2T
    float* msg2 = ws + 9289728;
    float* msg0 = ws + 10027008;
    int*   idx2 = (int*)(ws + 12386304);

    k_proj<<<dim3(288,3), 256, 0, stream>>>(x, tg, Wq, Wk, Wv, q0, k0, v0);
    k_pool01<<<432, 256, 0, stream>>>((const float4*)q0, (float4*)q1,
                                      (float4*)q2, (float4*)k2, (float4*)v2);
    k_attn2<<<dim3(16,72), 256, 0, stream>>>(q2, k2, v2, msg2, idx2);
    k_ref10<<<4608, 256, 0, stream>>>(q1, k1, v1, q0, k0, v0, msg2, idx2, msg0);
    k_out<<<288, 256, 0, stream>>>(msg0, Wo, bo, (float*)d_out);
}

// Round 12
// 206.395 us; speedup vs baseline: 1.0106x; 1.0106x over previous
//
#include <hip/hip_runtime.h>

#define NB   2
#define NHD  8
#define BH   16
#define HD   16
#define N0   9216
#define N1   2304
#define N2   576
#define W0_  96
#define W1_  48
#define W2_  24
#define M_TOT 18432
#define TEMP 0.25f

// exact k-th largest of the 64 per-lane values v (multiset semantics, duplicates counted).
// 2-bit-radix MSB-first ballot search on an order-isomorphic uint mapping: per step the
// three candidate ballots depend only on the previous g (not on each other), so the
// dependent chain is 16 steps instead of 32. Greedy MSB-first over 2-bit digits returns
// the exact k-th largest (same greedy invariant as 1-bit) -> result bit-identical.
__device__ __forceinline__ float kth_largest64(float v, int k){
    unsigned b = __float_as_uint(v);
    unsigned u = (b & 0x80000000u) ? ~b : (b | 0x80000000u);
    unsigned g = 0u;
#pragma unroll
    for(int p=30; p>=0; p-=2){
        unsigned c1 = g | (1u<<p);
        unsigned c2 = g | (2u<<p);
        unsigned c3 = g | (3u<<p);
        int n1 = (int)__popcll(__ballot(u >= c1));
        int n2 = (int)__popcll(__ballot(u >= c2));
        int n3 = (int)__popcll(__ballot(u >= c3));
        g = (n3 >= k) ? c3 : ((n2 >= k) ? c2 : ((n1 >= k) ? c1 : g));
    }
    unsigned rb = (g & 0x80000000u) ? (g & 0x7FFFFFFFu) : ~g;
    return __uint_as_float(rb);
}

// integer-exact exclusive wave scan of small counts (ci <= 15) via 4 ballots + mbcnt;
// replaces a 6-step dependent __shfl_up chain. Also returns the wave total C.
__device__ __forceinline__ void scan_counts64(int ci, int &excl, int &C){
    excl = 0; C = 0;
#pragma unroll
    for(int b=0;b<4;b++){
        unsigned long long mb = __ballot(((unsigned)ci>>b)&1u);
        int lt = __builtin_amdgcn_mbcnt_lo((unsigned)mb, 0);
        lt = __builtin_amdgcn_mbcnt_hi((unsigned)(mb>>32), lt);
        excl += lt << b;
        C += ((int)__popcll(mb)) << b;
    }
}

// ---------------- projection GEMM: dst[(b,h,n,d)] = sum_c A[m][c] * W[o][c] ----------------
// 64x128 tile (verified layout); staging loads for the next K-slab are issued right after the
// first barrier so they hide under the 16-kk math. FMA order bit-identical.
__global__ __launch_bounds__(256) void k_proj(const float* __restrict__ x, const float* __restrict__ tg,
    const float* __restrict__ Wq, const float* __restrict__ Wk, const float* __restrict__ Wv,
    float* __restrict__ q0, float* __restrict__ k0, float* __restrict__ v0)
{
    __shared__ __align__(16) float At[16][68];   // [k][row]
    __shared__ __align__(16) float Wt[16][132];  // [k][o]
    const int t = threadIdx.x;
    const int which = blockIdx.y;
    const float* A  = (which==0)? x : tg;
    const float* Wm = (which==0)? Wq : (which==1? Wk : Wv);
    float* dst      = (which==0)? q0 : (which==1? k0 : v0);
    const int m0 = blockIdx.x * 64;
    const int tx = t & 15, ty = t >> 4;

    float acc[4][8];
#pragma unroll
    for(int i=0;i<4;i++)
#pragma unroll
        for(int j=0;j<8;j++) acc[i][j]=0.f;

    const int ar = t>>2, akq = (t&3)*4;
    const int wo = t>>1, wkq = (t&1)*8;

    float4 av = *(const float4*)(A + (m0+ar)*128 + akq);
    float4 w0 = *(const float4*)(Wm + wo*128 + wkq);
    float4 w1 = *(const float4*)(Wm + wo*128 + wkq + 4);

    for(int kc=0;kc<128;kc+=16){
        At[akq+0][ar] = av.x;
        At[akq+1][ar] = av.y;
        At[akq+2][ar] = av.z;
        At[akq+3][ar] = av.w;
        Wt[wkq+0][wo] = w0.x; Wt[wkq+1][wo] = w0.y;
        Wt[wkq+2][wo] = w0.z; Wt[wkq+3][wo] = w0.w;
        Wt[wkq+4][wo] = w1.x; Wt[wkq+5][wo] = w1.y;
        Wt[wkq+6][wo] = w1.z; Wt[wkq+7][wo] = w1.w;
        __syncthreads();
        float4 nav, nw0, nw1;
        if (kc < 112){   // issue next slab's loads; they complete under the kk math
            nav = *(const float4*)(A + (m0+ar)*128 + kc+16 + akq);
            nw0 = *(const float4*)(Wm + wo*128 + kc+16 + wkq);
            nw1 = *(const float4*)(Wm + wo*128 + kc+16 + wkq + 4);
        }
#pragma unroll
        for(int kk=0;kk<16;kk++){
            float4 a4 = *(const float4*)&At[kk][ty*4];
            float4 wa = *(const float4*)&Wt[kk][tx*4];
            float4 wb = *(const float4*)&Wt[kk][64 + tx*4];
            float avr[4] = {a4.x,a4.y,a4.z,a4.w};
            float wvr[8] = {wa.x,wa.y,wa.z,wa.w, wb.x,wb.y,wb.z,wb.w};
#pragma unroll
            for(int i=0;i<4;i++)
#pragma unroll
                for(int j=0;j<8;j++) acc[i][j] += avr[i]*wvr[j];
        }
        __syncthreads();
        if (kc < 112){ av = nav; w0 = nw0; w1 = nw1; }
    }
    const int hA = tx>>2, dA = (tx&3)*4;
#pragma unroll
    for(int i=0;i<4;i++){
        int m = m0 + ty*4 + i;
        int b = m / N0; int n = m - b*N0;
        float4 sA = make_float4(acc[i][0], acc[i][1], acc[i][2], acc[i][3]);
        float4 sB = make_float4(acc[i][4], acc[i][5], acc[i][6], acc[i][7]);
        *(float4*)(dst + ((b*NHD + hA    )*N0 + n)*16 + dA) = sA;
        *(float4*)(dst + ((b*NHD + hA + 4)*N0 + n)*16 + dA) = sB;
    }
}

// ---- FUSED pooling: level0 -> level1 (row layout) AND level1 -> level2 (q row, k/v transposed) ----
__global__ __launch_bounds__(256) void k_pool01(const float4* __restrict__ src0,
    float4* __restrict__ dst1, float4* __restrict__ q2f,
    float4* __restrict__ k2T, float4* __restrict__ v2T)
{
    int tid = blockIdx.x*256 + threadIdx.x;
    if (tid >= 110592) return;
    int d4 = tid & 3;
    int rest = tid >> 2;
    int n2 = rest % N2; int g = rest / N2;     // g in [0,48): 0-15 q, 16-31 k, 32-47 v
    int yo2 = n2 / W2_, xo2 = n2 - yo2*W2_;

    const float4* s = src0 + g*N0*4;
    float4* d1 = dst1 + g*N1*4;
    float4 l1[4];
#pragma unroll
    for(int yy=0;yy<2;yy++){
#pragma unroll
        for(int xx=0;xx<2;xx++){
            int y1 = 2*yo2+yy, x1 = 2*xo2+xx;
            int n1 = y1*W1_ + x1;
            int cbase = (2*y1)*W0_ + 2*x1;
            float4 a = s[(cbase       )*4 + d4];
            float4 b = s[(cbase+1     )*4 + d4];
            float4 c = s[(cbase+W0_   )*4 + d4];
            float4 d = s[(cbase+W0_+1 )*4 + d4];
            float4 o;
            o.x = 0.25f*(a.x+b.x+c.x+d.x);
            o.y = 0.25f*(a.y+b.y+c.y+d.y);
            o.z = 0.25f*(a.z+b.z+c.z+d.z);
            o.w = 0.25f*(a.w+b.w+c.w+d.w);
            d1[n1*4 + d4] = o;
            l1[yy*2+xx] = o;
        }
    }
    float4 o2;
    o2.x = 0.25f*(l1[0].x+l1[1].x+l1[2].x+l1[3].x);
    o2.y = 0.25f*(l1[0].y+l1[1].y+l1[2].y+l1[3].y);
    o2.z = 0.25f*(l1[0].z+l1[1].z+l1[2].z+l1[3].z);
    o2.w = 0.25f*(l1[0].w+l1[1].w+l1[2].w+l1[3].w);
    int grp = g >> 4, bh = g & 15;
    if (grp == 0)      q2f[(bh*N2 + n2)*4 + d4] = o2;
    else if (grp == 1) k2T[(bh*4 + d4)*N2 + n2] = o2;
    else               v2T[(bh*4 + d4)*N2 + n2] = o2;
}

// threshold-pruned exact top-16 of 576 exp-values (9 per lane), tie-break smaller global index.
__device__ __forceinline__ void top16_sel(const float ev[9], int lane, float* cv, int* cx, int* ip)
{
    // 1. per-lane head
    float head = ev[0];
#pragma unroll
    for(int i=1;i<9;i++) head = fmaxf(head, ev[i]);

    // 2. T = exact 16th-largest head (ballot radix search)
    float T = kth_largest64(head, 16);   // >=16 values are >= T -> top-16 subset of candidates

    // 3. per-lane candidate count + ballot-based exclusive scan (integer-exact)
    int ci = 0;
#pragma unroll
    for(int i=0;i<9;i++) ci += (ev[i] >= T) ? 1 : 0;
    int excl, C;
    scan_counts64(ci, excl, C);          // C >= 16 guaranteed

    // 4. deposit candidates into this wave's LDS region; pad 4 sentinels
    int o = excl;
#pragma unroll
    for(int i=0;i<9;i++){
        if (ev[i] >= T){
            cv[o] = ev[i];
            cx[o] = i*64 + lane;
            o++;
        }
    }
    if (lane < 4){ cv[C+lane] = -1.0f; cx[C+lane] = 0x7fffffff; }
    // in-wave DS ordering: reads below are same-wave, issued after the writes

    // 5. rank each candidate against all candidates (broadcast float4 scans)
    for(int l=lane; l<C; l+=64){
        float mv = cv[l]; int mi = cx[l];
        int rank = 0;
        for(int c=0;c<C;c+=4){
            float4 vv = *(const float4*)(cv + c);
            int4   ii = *(const int4*)(cx + c);
            rank += (vv.x > mv || (vv.x == mv && ii.x < mi)) ? 1 : 0;
            rank += (vv.y > mv || (vv.y == mv && ii.y < mi)) ? 1 : 0;
            rank += (vv.z > mv || (vv.z == mv && ii.z < mi)) ? 1 : 0;
            rank += (vv.w > mv || (vv.w == mv && ii.w < mi)) ? 1 : 0;
        }
        if (rank < 16) ip[rank] = mi;
    }
}

// register ping-pong staging (round-4 verified schedule): scheduling-only, arithmetic
// identical to the two-pass max-shift version -> selection values unchanged.
#define LOADK(KB, T9) { int m_=(T9)*64+lane; \
    KB[0]=kT[0*N2+m_]; KB[1]=kT[1*N2+m_]; KB[2]=kT[2*N2+m_]; KB[3]=kT[3*N2+m_]; }
#define LOADV(VB, T9) { int m_=(T9)*64+lane; \
    VB[0]=vT[0*N2+m_]; VB[1]=vT[1*N2+m_]; VB[2]=vT[2*N2+m_]; VB[3]=vT[3*N2+m_]; }
#define STEPK(T9, KB) { float sA=0.f, sB=0.f; \
    _Pragma("unroll") \
    for(int dg=0;dg<4;dg++){ float4 kv=KB[dg]; \
      sA += qrA[dg*4+0]*kv.x + qrA[dg*4+1]*kv.y + qrA[dg*4+2]*kv.z + qrA[dg*4+3]*kv.w; \
      sB += qrB[dg*4+0]*kv.x + qrB[dg*4+1]*kv.y + qrB[dg*4+2]*kv.z + qrB[dg*4+3]*kv.w; } \
    sA *= TEMP; sB *= TEMP; \
    evA[T9]=sA; evB[T9]=sB; \
    mxA = fmaxf(mxA, sA); mxB = fmaxf(mxB, sB); }
#define STEPV(T9, VB) { \
    float eA=expf(evA[T9]-mxA), eB=expf(evB[T9]-mxB); \
    evA[T9]=eA; evB[T9]=eB; sumA+=eA; sumB+=eB; \
    _Pragma("unroll") \
    for(int dg=0;dg<4;dg++){ float4 vv=VB[dg]; \
      accA[dg*4+0]+=eA*vv.x; accA[dg*4+1]+=eA*vv.y; accA[dg*4+2]+=eA*vv.z; accA[dg*4+3]+=eA*vv.w; \
      accB[dg*4+0]+=eB*vv.x; accB[dg*4+1]+=eB*vv.y; accB[dg*4+2]+=eB*vv.z; accB[dg*4+3]+=eB*vv.w; } }

// ---- level-2 full attention + top-16: 2 queries/wave, two passes with max-shift, register
// ping-pong double-buffer per pass (k loads overlap score FMAs; v loads overlap exp+PV). ----
__global__ __launch_bounds__(256) void k_attn2(const float* __restrict__ q2, const float* __restrict__ k2,
    const float* __restrict__ v2, float* __restrict__ msg2, int* __restrict__ idx2)
{
    __shared__ __align__(16) float cval[4][580];
    __shared__ __align__(16) int   cidx[4][580];
    const int bh = blockIdx.x;
    const int wv = threadIdx.x>>6, lane = threadIdx.x&63;
    const int qA = blockIdx.y*8 + wv*2;   // two queries per wave
    const int qB = qA + 1;

    float qrA[16], qrB[16];
    {
        const float4* qpA = (const float4*)(q2 + (bh*N2 + qA)*16);
        const float4* qpB = (const float4*)(q2 + (bh*N2 + qB)*16);
#pragma unroll
        for(int dq=0;dq<4;dq++){
            float4 va = qpA[dq];
            qrA[dq*4+0]=va.x; qrA[dq*4+1]=va.y; qrA[dq*4+2]=va.z; qrA[dq*4+3]=va.w;
            float4 vb = qpB[dq];
            qrB[dq*4+0]=vb.x; qrB[dq*4+1]=vb.y; qrB[dq*4+2]=vb.z; qrB[dq*4+3]=vb.w;
        }
    }

    const float4* kT = (const float4*)k2 + bh*4*N2;   // [dg][m]
    const float4* vT = (const float4*)v2 + bh*4*N2;

    // ---- pass 1: scores + running max (k ping-pong) ----
    float evA[9], evB[9];
    float mxA = -1e30f, mxB = -1e30f;
    {
        float4 ka[4], kb[4];
        LOADK(ka, 0);
#pragma unroll
        for(int t2=0;t2<4;t2++){
            LOADK(kb, 2*t2+1);
            STEPK(2*t2, ka);
            LOADK(ka, 2*t2+2);
            STEPK(2*t2+1, kb);
        }
        STEPK(8, ka);
    }
#pragma unroll
    for(int st=1; st<64; st<<=1){
        mxA = fmaxf(mxA, __shfl_xor(mxA, st));
        mxB = fmaxf(mxB, __shfl_xor(mxB, st));
    }

    // ---- pass 2: exp + PV accumulate (v ping-pong) ----
    float sumA=0.f, sumB=0.f;
    float accA[16], accB[16];
#pragma unroll
    for(int d=0;d<16;d++){ accA[d]=0.f; accB[d]=0.f; }
    {
        float4 va_[4], vb[4];
        LOADV(va_, 0);
#pragma unroll
        for(int t2=0;t2<4;t2++){
            LOADV(vb, 2*t2+1);
            STEPV(2*t2, va_);
            LOADV(va_, 2*t2+2);
            STEPV(2*t2+1, vb);
        }
        STEPV(8, va_);
    }
#pragma unroll
    for(int st=1; st<64; st<<=1){
        sumA += __shfl_xor(sumA, st);
        sumB += __shfl_xor(sumB, st);
    }

    // ---- tree-reduce 16-dim accumulators over 64 lanes, A and B interleaved ----
    const bool b5 = (lane & 32) != 0;
    const bool b4 = (lane & 16) != 0;
    const bool b3 = (lane & 8) != 0;
    const bool b2 = (lane & 4) != 0;
    float r8A[8], r8B[8];
#pragma unroll
    for(int i=0;i<8;i++){
        float sndA  = b5 ? accA[i]   : accA[i+8];
        float keptA = b5 ? accA[i+8] : accA[i];
        r8A[i] = keptA + __shfl_xor(sndA, 32);
        float sndB  = b5 ? accB[i]   : accB[i+8];
        float keptB = b5 ? accB[i+8] : accB[i];
        r8B[i] = keptB + __shfl_xor(sndB, 32);
    }
    float r4A[4], r4B[4];
#pragma unroll
    for(int i=0;i<4;i++){
        float sndA  = b4 ? r8A[i]   : r8A[i+4];
        float keptA = b4 ? r8A[i+4] : r8A[i];
        r4A[i] = keptA + __shfl_xor(sndA, 16);
        float sndB  = b4 ? r8B[i]   : r8B[i+4];
        float keptB = b4 ? r8B[i+4] : r8B[i];
        r4B[i] = keptB + __shfl_xor(sndB, 16);
    }
    float r2A[2], r2B[2];
#pragma unroll
    for(int i=0;i<2;i++){
        float sndA  = b3 ? r4A[i]   : r4A[i+2];
        float keptA = b3 ? r4A[i+2] : r4A[i];
        r2A[i] = keptA + __shfl_xor(sndA, 8);
        float sndB  = b3 ? r4B[i]   : r4B[i+2];
        float keptB = b3 ? r4B[i+2] : r4B[i];
        r2B[i] = keptB + __shfl_xor(sndB, 8);
    }
    {
        float sndA  = b2 ? r2A[0] : r2A[1];
        float keptA = b2 ? r2A[1] : r2A[0];
        r2A[0] = keptA + __shfl_xor(sndA, 4);
        float sndB  = b2 ? r2B[0] : r2B[1];
        float keptB = b2 ? r2B[1] : r2B[0];
        r2B[0] = keptB + __shfl_xor(sndB, 4);
    }
    r2A[0] += __shfl_xor(r2A[0], 2);
    r2B[0] += __shfl_xor(r2B[0], 2);
    r2A[0] += __shfl_xor(r2A[0], 1);
    r2B[0] += __shfl_xor(r2B[0], 1);
    float invA = 1.0f/sumA, invB = 1.0f/sumB;
    if ((lane&3)==0){
        msg2[(bh*N2+qA)*16 + (lane>>2)] = r2A[0]*invA;
        msg2[(bh*N2+qB)*16 + (lane>>2)] = r2B[0]*invB;
    }

    // ---- top-16 for both queries (sequential reuse of per-wave LDS region) ----
    top16_sel(evA, lane, cval[wv], cidx[wv], idx2 + (bh*N2+qA)*16);
    top16_sel(evB, lane, cval[wv], cidx[wv], idx2 + (bh*N2+qB)*16);
}

// ---- FUSED refinement: wave owns 1 parent + its 4 children; shared candidate set, no barrier ----
// Selection ranks on raw s (kth ballot), so __expf (message values only) is safe here.
__global__ __launch_bounds__(256) void k_ref10(
    const float* __restrict__ q1, const float* __restrict__ k1, const float* __restrict__ v1,
    const float* __restrict__ q0, const float* __restrict__ k0, const float* __restrict__ v0,
    const float* __restrict__ msg2, const int* __restrict__ idx2, float* __restrict__ msg0)
{
    __shared__ float msg1s[4][16];
    __shared__ int   idx1s[4][8];
    // XCD swizzle: 9216 blocks = 8 x 1152; each XCD owns 2 contiguous bh
    const int bid = (blockIdx.x & 7)*1152 + (blockIdx.x >> 3);
    const int bh = bid / 576, tile = bid - bh*576;
    const int tyy = tile / 24, txx = tile - tyy*24;
    const int py0 = tyy*2, px0 = txx*2;      // 2x2 parent tile origin (level-1 coords)
    const int wv = threadIdx.x>>6, lane = threadIdx.x&63;

    const int ppy = py0 + (wv>>1), ppx = px0 + (wv&1);   // this wave's parent (level-1)

    // ---------- phase 1: ref1 for parent wv ----------
    {
        const int n  = ppy*W1_ + ppx;
        const int par = (ppy>>1)*W2_ + (ppx>>1);
        const int kk = lane>>2, tt = lane&3, dy = tt>>1, dx = tt&1;
        int p = idx2[(bh*N2+par)*16 + kk];
        int ky = p / W2_, kx = p - ky*W2_;
        int child = (2*ky+dy)*W1_ + 2*kx+dx;

        const float* qp = q1 + (bh*N1+n)*16;
        float qr[16];
#pragma unroll
        for(int d=0; d<16; d+=4){
            float4 qq = *(const float4*)(qp+d);
            qr[d]=qq.x; qr[d+1]=qq.y; qr[d+2]=qq.z; qr[d+3]=qq.w;
        }
        const float4* kp = (const float4*)(k1 + (bh*N1+child)*16);
        float s = 0.f;
#pragma unroll
        for(int dq=0;dq<4;dq++){
            float4 kv = kp[dq];
            s += qr[dq*4+0]*kv.x + qr[dq*4+1]*kv.y + qr[dq*4+2]*kv.z + qr[dq*4+3]*kv.w;
        }
        s *= TEMP;

        // top-8 SET selection hoisted before the softmax reduction (VALU/SALU chain overlaps
        // the DS-pipe shuffle trees below).
        float T8 = kth_largest64(s, 8);
        unsigned long long mgt = __ballot(s > T8);
        unsigned long long meq = __ballot(s == T8);
        int ngt = (int)__popcll(mgt);
        int ltg = __builtin_amdgcn_mbcnt_lo((unsigned)mgt, 0);
        ltg = __builtin_amdgcn_mbcnt_hi((unsigned)(mgt>>32), ltg);
        int lte = __builtin_amdgcn_mbcnt_lo((unsigned)meq, 0);
        lte = __builtin_amdgcn_mbcnt_hi((unsigned)(meq>>32), lte);
        int slot = (s > T8) ? ltg : ((s == T8) ? (ngt + lte) : 8);
        if (slot < 8) idx1s[wv][slot] = child;

        float e = __expf(s);
        float sum = e;
#pragma unroll
        for(int st=1; st<64; st<<=1) sum += __shfl_xor(sum, st);

        float acc[16];
        const float4* vp = (const float4*)(v1 + (bh*N1+child)*16);
#pragma unroll
        for(int dq=0;dq<4;dq++){
            float4 vv = vp[dq];
            acc[dq*4+0]=e*vv.x; acc[dq*4+1]=e*vv.y; acc[dq*4+2]=e*vv.z; acc[dq*4+3]=e*vv.w;
        }
        const bool b5 = (lane & 32) != 0;
        float r8[8];
#pragma unroll
        for(int ii=0;ii<8;ii++){
            float snd  = b5 ? acc[ii]   : acc[ii+8];
            float kept = b5 ? acc[ii+8] : acc[ii];
            r8[ii] = kept + __shfl_xor(snd, 32);
        }
        const bool b4 = (lane & 16) != 0;
        float r4[4];
#pragma unroll
        for(int ii=0;ii<4;ii++){
            float snd  = b4 ? r8[ii]   : r8[ii+4];
            float kept = b4 ? r8[ii+4] : r8[ii];
            r4[ii] = kept + __shfl_xor(snd, 16);
        }
        const bool b3 = (lane & 8) != 0;
        float r2[2];
#pragma unroll
        for(int ii=0;ii<2;ii++){
            float snd  = b3 ? r4[ii]   : r4[ii+2];
            float kept = b3 ? r4[ii+2] : r4[ii];
            r2[ii] = kept + __shfl_xor(snd, 8);
        }
        const bool b2 = (lane & 4) != 0;
        {
            float snd  = b2 ? r2[0] : r2[1];
            float kept = b2 ? r2[1] : r2[0];
            r2[0] = kept + __shfl_xor(snd, 4);
        }
        r2[0] += __shfl_xor(r2[0], 2);
        r2[0] += __shfl_xor(r2[0], 1);

        float inv1 = 1.0f/sum;
        if ((lane&3)==0){
            int d = lane>>2;
            msg1s[wv][d] = msg2[(bh*N2+par)*16 + d] + r2[0]*inv1;
        }
    }
    // no __syncthreads: each wave reads only its own msg1s[wv]/idx1s[wv] (in-wave DS order)

    // ---------- phase 2: this parent's 4 children; both query-iterations' reductions interleaved ----------
    const int j = lane & 31, sub = lane >> 5;
    const int kk = j>>2, tt = j&3, dy = tt>>1, dx = tt&1;
    int p = idx1s[wv][kk];
    int ky = p / W1_, kx = p - ky*W1_;
    int child = (2*ky+dy)*W0_ + 2*kx+dx;

    float kr[16];
    {
        const float4* kp = (const float4*)(k0 + (bh*N0+child)*16);
#pragma unroll
        for(int dq=0;dq<4;dq++){
            float4 kv = kp[dq];
            kr[dq*4+0]=kv.x; kr[dq*4+1]=kv.y; kr[dq*4+2]=kv.z; kr[dq*4+3]=kv.w;
        }
    }
    const int cy0 = 2*ppy, cx0 = 2*ppx + sub;
    int nq[2];
    float s_[2];
#pragma unroll
    for(int it=0; it<2; it++){
        nq[it] = (cy0+it)*W0_ + cx0;
        const float* qp = q0 + (bh*N0+nq[it])*16;
        float qr[16];
#pragma unroll
        for(int d=0; d<16; d+=4){
            float4 qq = *(const float4*)(qp+d);
            qr[d]=qq.x; qr[d+1]=qq.y; qr[d+2]=qq.z; qr[d+3]=qq.w;
        }
        float s = 0.f;
#pragma unroll
        for(int dq=0;dq<4;dq++){
            s += qr[dq*4+0]*kr[dq*4+0] + qr[dq*4+1]*kr[dq*4+1]
               + qr[dq*4+2]*kr[dq*4+2] + qr[dq*4+3]*kr[dq*4+3];
        }
        s_[it] = s * TEMP;
    }
    float vr[16];
    {
        const float4* vp = (const float4*)(v0 + (bh*N0+child)*16);
#pragma unroll
        for(int dq=0;dq<4;dq++){
            float4 vv = vp[dq];
            vr[dq*4+0]=vv.x; vr[dq*4+1]=vv.y; vr[dq*4+2]=vv.z; vr[dq*4+3]=vv.w;
        }
    }
    const float m1d = msg1s[wv][j>>1];

    float e0 = __expf(s_[0]);
    float e1 = __expf(s_[1]);
    float sum0 = e0, sum1 = e1;
#pragma unroll
    for(int st=1; st<32; st<<=1){
        sum0 += __shfl_xor(sum0, st);
        sum1 += __shfl_xor(sum1, st);
    }

    float acc0[16], acc1[16];
#pragma unroll
    for(int d=0;d<16;d++){ acc0[d] = e0*vr[d]; acc1[d] = e1*vr[d]; }

    const bool c4 = (j & 16) != 0;
    float p8A[8], p8B[8];
#pragma unroll
    for(int ii=0;ii<8;ii++){
        float sndA  = c4 ? acc0[ii]   : acc0[ii+8];
        float keptA = c4 ? acc0[ii+8] : acc0[ii];
        p8A[ii] = keptA + __shfl_xor(sndA, 16);
        float sndB  = c4 ? acc1[ii]   : acc1[ii+8];
        float keptB = c4 ? acc1[ii+8] : acc1[ii];
        p8B[ii] = keptB + __shfl_xor(sndB, 16);
    }
    const bool c3 = (j & 8) != 0;
    float p4A[4], p4B[4];
#pragma unroll
    for(int ii=0;ii<4;ii++){
        float sndA  = c3 ? p8A[ii]   : p8A[ii+4];
        float keptA = c3 ? p8A[ii+4] : p8A[ii];
        p4A[ii] = keptA + __shfl_xor(sndA, 8);
        float sndB  = c3 ? p8B[ii]   : p8B[ii+4];
        float keptB = c3 ? p8B[ii+4] : p8B[ii];
        p4B[ii] = keptB + __shfl_xor(sndB, 8);
    }
    const bool c2 = (j & 4) != 0;
    float p2A[2], p2B[2];
#pragma unroll
    for(int ii=0;ii<2;ii++){
        float sndA  = c2 ? p4A[ii]   : p4A[ii+2];
        float keptA = c2 ? p4A[ii+2] : p4A[ii];
        p2A[ii] = keptA + __shfl_xor(sndA, 4);
        float sndB  = c2 ? p4B[ii]   : p4B[ii+2];
        float keptB = c2 ? p4B[ii+2] : p4B[ii];
        p2B[ii] = keptB + __shfl_xor(sndB, 4);
    }
    const bool c1 = (j & 2) != 0;
    {
        float sndA  = c1 ? p2A[0] : p2A[1];
        float keptA = c1 ? p2A[1] : p2A[0];
        p2A[0] = keptA + __shfl_xor(sndA, 2);
        float sndB  = c1 ? p2B[0] : p2B[1];
        float keptB = c1 ? p2B[1] : p2B[0];
        p2B[0] = keptB + __shfl_xor(sndB, 2);
    }
    p2A[0] += __shfl_xor(p2A[0], 1);
    p2B[0] += __shfl_xor(p2B[0], 1);

    float inv0 = 1.0f/sum0, inv1 = 1.0f/sum1;
    if ((j&1)==0){
        int d = j>>1;
        int b_ = bh>>3, h = bh&7;
        msg0[(b_*N0+nq[0])*128 + h*16 + d] = m1d + p2A[0]*inv0;
        msg0[(b_*N0+nq[1])*128 + h*16 + d] = m1d + p2B[0]*inv1;
    }
}

// ---------------- output projection GEMM + bias (same staging prefetch as k_proj) ----------------
__global__ __launch_bounds__(256) void k_out(const float* __restrict__ msg0, const float* __restrict__ Wo,
    const float* __restrict__ bo, float* __restrict__ out)
{
    __shared__ __align__(16) float At[16][68];
    __shared__ __align__(16) float Wt[16][132];
    const int t = threadIdx.x;
    const int m0 = blockIdx.x * 64;
    const int tx = t & 15, ty = t >> 4;

    float acc[4][8];
#pragma unroll
    for(int i=0;i<4;i++)
#pragma unroll
        for(int j=0;j<8;j++) acc[i][j]=0.f;

    const int ar = t>>2, akq = (t&3)*4;
    const int wo = t>>1, wkq = (t&1)*8;

    float4 av = *(const float4*)(msg0 + (m0+ar)*128 + akq);
    float4 w0 = *(const float4*)(Wo + wo*128 + wkq);
    float4 w1 = *(const float4*)(Wo + wo*128 + wkq + 4);

    for(int kc=0;kc<128;kc+=16){
        At[akq+0][ar] = av.x;
        At[akq+1][ar] = av.y;
        At[akq+2][ar] = av.z;
        At[akq+3][ar] = av.w;
        Wt[wkq+0][wo] = w0.x; Wt[wkq+1][wo] = w0.y;
        Wt[wkq+2][wo] = w0.z; Wt[wkq+3][wo] = w0.w;
        Wt[wkq+4][wo] = w1.x; Wt[wkq+5][wo] = w1.y;
        Wt[wkq+6][wo] = w1.z; Wt[wkq+7][wo] = w1.w;
        __syncthreads();
        float4 nav, nw0, nw1;
        if (kc < 112){
            nav = *(const float4*)(msg0 + (m0+ar)*128 + kc+16 + akq);
            nw0 = *(const float4*)(Wo + wo*128 + kc+16 + wkq);
            nw1 = *(const float4*)(Wo + wo*128 + kc+16 + wkq + 4);
        }
#pragma unroll
        for(int kk=0;kk<16;kk++){
            float4 a4 = *(const float4*)&At[kk][ty*4];
            float4 wa = *(const float4*)&Wt[kk][tx*4];
            float4 wb = *(const float4*)&Wt[kk][64 + tx*4];
            float avr[4] = {a4.x,a4.y,a4.z,a4.w};
            float wvr[8] = {wa.x,wa.y,wa.z,wa.w, wb.x,wb.y,wb.z,wb.w};
#pragma unroll
            for(int i=0;i<4;i++)
#pragma unroll
                for(int j=0;j<8;j++) acc[i][j] += avr[i]*wvr[j];
        }
        __syncthreads();
        if (kc < 112){ av = nav; w0 = nw0; w1 = nw1; }
    }
#pragma unroll
    for(int i=0;i<4;i++){
        int m = m0 + ty*4 + i;
        float4 sA = make_float4(acc[i][0]+bo[tx*4+0], acc[i][1]+bo[tx*4+1],
                                acc[i][2]+bo[tx*4+2], acc[i][3]+bo[tx*4+3]);
        float4 sB = make_float4(acc[i][4]+bo[64+tx*4+0], acc[i][5]+bo[64+tx*4+1],
                                acc[i][6]+bo[64+tx*4+2], acc[i][7]+bo[64+tx*4+3]);
        *(float4*)(out + m*128 + tx*4)      = sA;
        *(float4*)(out + m*128 + 64 + tx*4) = sB;
    }
}

extern "C" void kernel_launch(void* const* d_in, const int* in_sizes, int n_in,
                              void* d_out, int out_size, void* d_ws, size_t ws_size,
                              hipStream_t stream) {
    const float* x  = (const float*)d_in[0];
    const float* tg = (const float*)d_in[1];
    const float* Wq = (const float*)d_in[2];
    const float* Wk = (const float*)d_in[3];
    const float* Wv = (const float*)d_in[4];
    const float* Wo = (const float*)d_in[5];
    const float* bo = (const float*)d_in[6];

    float* ws = (float*)d_ws;
    float* q0   = ws + 0;
    float* k0   = ws + 2359296;
    float* v0   = ws + 4718592;
    float* q1   = ws + 7077888;
    float* k1   = ws + 7667712;
    float* v1   = ws + 8257536;
    float* q2   = ws + 8847360;
    float* k2   = ws + 8994816;   // k2T [bh][dg][m] float4
    float* v2   = ws + 9142272;   // v2T
    float* msg2 = ws + 9289728;
    float* msg0 = ws + 10027008;
    int*   idx2 = (int*)(ws + 12386304);

    k_proj<<<dim3(288,3), 256, 0, stream>>>(x, tg, Wq, Wk, Wv, q0, k0, v0);
    k_pool01<<<432, 256, 0, stream>>>((const float4*)q0, (float4*)q1,
                                      (float4*)q2, (float4*)k2, (float4*)v2);
    k_attn2<<<dim3(16,72), 256, 0, stream>>>(q2, k2, v2, msg2, idx2);
    k_ref10<<<9216, 256, 0, stream>>>(q1, k1, v1, q0, k0, v0, msg2, idx2, msg0);
    k_out<<<288, 256, 0, stream>>>(msg0, Wo, bo, (float*)d_out);
}

// Round 14
// 201.026 us; speedup vs baseline: 1.0376x; 1.0267x over previous
//
#include <hip/hip_runtime.h>

#define NB   2
#define NHD  8
#define BH   16
#define HD   16
#define N0   9216
#define N1   2304
#define N2   576
#define W0_  96
#define W1_  48
#define W2_  24
#define M_TOT 18432
#define TEMP 0.25f

// exact k-th largest of the 64 per-lane values v (multiset semantics, duplicates counted).
// 2-bit-radix MSB-first ballot search on an order-isomorphic uint mapping: per step the
// three candidate ballots depend only on the previous g (not on each other), so the
// dependent chain is 16 steps instead of 32. Greedy MSB-first over 2-bit digits returns
// the exact k-th largest (same greedy invariant as 1-bit) -> result bit-identical.
__device__ __forceinline__ float kth_largest64(float v, int k){
    unsigned b = __float_as_uint(v);
    unsigned u = (b & 0x80000000u) ? ~b : (b | 0x80000000u);
    unsigned g = 0u;
#pragma unroll
    for(int p=30; p>=0; p-=2){
        unsigned c1 = g | (1u<<p);
        unsigned c2 = g | (2u<<p);
        unsigned c3 = g | (3u<<p);
        int n1 = (int)__popcll(__ballot(u >= c1));
        int n2 = (int)__popcll(__ballot(u >= c2));
        int n3 = (int)__popcll(__ballot(u >= c3));
        g = (n3 >= k) ? c3 : ((n2 >= k) ? c2 : ((n1 >= k) ? c1 : g));
    }
    unsigned rb = (g & 0x80000000u) ? (g & 0x7FFFFFFFu) : ~g;
    return __uint_as_float(rb);
}

// integer-exact exclusive wave scan of small counts (ci <= 15) via 4 ballots + mbcnt;
// replaces a 6-step dependent __shfl_up chain. Also returns the wave total C.
__device__ __forceinline__ void scan_counts64(int ci, int &excl, int &C){
    excl = 0; C = 0;
#pragma unroll
    for(int b=0;b<4;b++){
        unsigned long long mb = __ballot(((unsigned)ci>>b)&1u);
        int lt = __builtin_amdgcn_mbcnt_lo((unsigned)mb, 0);
        lt = __builtin_amdgcn_mbcnt_hi((unsigned)(mb>>32), lt);
        excl += lt << b;
        C += ((int)__popcll(mb)) << b;
    }
}

// ---------------- projection GEMM: dst[(b,h,n,d)] = sum_c A[m][c] * W[o][c] ----------------
// 64x128 tile (verified layout); staging loads for the next K-slab are issued right after the
// first barrier so they hide under the 16-kk math. FMA order bit-identical.
__global__ __launch_bounds__(256) void k_proj(const float* __restrict__ x, const float* __restrict__ tg,
    const float* __restrict__ Wq, const float* __restrict__ Wk, const float* __restrict__ Wv,
    float* __restrict__ q0, float* __restrict__ k0, float* __restrict__ v0)
{
    __shared__ __align__(16) float At[16][68];   // [k][row]
    __shared__ __align__(16) float Wt[16][132];  // [k][o]
    const int t = threadIdx.x;
    const int which = blockIdx.y;
    const float* A  = (which==0)? x : tg;
    const float* Wm = (which==0)? Wq : (which==1? Wk : Wv);
    float* dst      = (which==0)? q0 : (which==1? k0 : v0);
    const int m0 = blockIdx.x * 64;
    const int tx = t & 15, ty = t >> 4;

    float acc[4][8];
#pragma unroll
    for(int i=0;i<4;i++)
#pragma unroll
        for(int j=0;j<8;j++) acc[i][j]=0.f;

    const int ar = t>>2, akq = (t&3)*4;
    const int wo = t>>1, wkq = (t&1)*8;

    float4 av = *(const float4*)(A + (m0+ar)*128 + akq);
    float4 w0 = *(const float4*)(Wm + wo*128 + wkq);
    float4 w1 = *(const float4*)(Wm + wo*128 + wkq + 4);

    for(int kc=0;kc<128;kc+=16){
        At[akq+0][ar] = av.x;
        At[akq+1][ar] = av.y;
        At[akq+2][ar] = av.z;
        At[akq+3][ar] = av.w;
        Wt[wkq+0][wo] = w0.x; Wt[wkq+1][wo] = w0.y;
        Wt[wkq+2][wo] = w0.z; Wt[wkq+3][wo] = w0.w;
        Wt[wkq+4][wo] = w1.x; Wt[wkq+5][wo] = w1.y;
        Wt[wkq+6][wo] = w1.z; Wt[wkq+7][wo] = w1.w;
        __syncthreads();
        float4 nav, nw0, nw1;
        if (kc < 112){   // issue next slab's loads; they complete under the kk math
            nav = *(const float4*)(A + (m0+ar)*128 + kc+16 + akq);
            nw0 = *(const float4*)(Wm + wo*128 + kc+16 + wkq);
            nw1 = *(const float4*)(Wm + wo*128 + kc+16 + wkq + 4);
        }
#pragma unroll
        for(int kk=0;kk<16;kk++){
            float4 a4 = *(const float4*)&At[kk][ty*4];
            float4 wa = *(const float4*)&Wt[kk][tx*4];
            float4 wb = *(const float4*)&Wt[kk][64 + tx*4];
            float avr[4] = {a4.x,a4.y,a4.z,a4.w};
            float wvr[8] = {wa.x,wa.y,wa.z,wa.w, wb.x,wb.y,wb.z,wb.w};
#pragma unroll
            for(int i=0;i<4;i++)
#pragma unroll
                for(int j=0;j<8;j++) acc[i][j] += avr[i]*wvr[j];
        }
        __syncthreads();
        if (kc < 112){ av = nav; w0 = nw0; w1 = nw1; }
    }
    const int hA = tx>>2, dA = (tx&3)*4;
#pragma unroll
    for(int i=0;i<4;i++){
        int m = m0 + ty*4 + i;
        int b = m / N0; int n = m - b*N0;
        float4 sA = make_float4(acc[i][0], acc[i][1], acc[i][2], acc[i][3]);
        float4 sB = make_float4(acc[i][4], acc[i][5], acc[i][6], acc[i][7]);
        *(float4*)(dst + ((b*NHD + hA    )*N0 + n)*16 + dA) = sA;
        *(float4*)(dst + ((b*NHD + hA + 4)*N0 + n)*16 + dA) = sB;
    }
}

// ---- FUSED pooling: level0 -> level1 (row layout) AND level1 -> level2 (q row, k/v transposed) ----
__global__ __launch_bounds__(256) void k_pool01(const float4* __restrict__ src0,
    float4* __restrict__ dst1, float4* __restrict__ q2f,
    float4* __restrict__ k2T, float4* __restrict__ v2T)
{
    int tid = blockIdx.x*256 + threadIdx.x;
    if (tid >= 110592) return;
    int d4 = tid & 3;
    int rest = tid >> 2;
    int n2 = rest % N2; int g = rest / N2;     // g in [0,48): 0-15 q, 16-31 k, 32-47 v
    int yo2 = n2 / W2_, xo2 = n2 - yo2*W2_;

    const float4* s = src0 + g*N0*4;
    float4* d1 = dst1 + g*N1*4;
    float4 l1[4];
#pragma unroll
    for(int yy=0;yy<2;yy++){
#pragma unroll
        for(int xx=0;xx<2;xx++){
            int y1 = 2*yo2+yy, x1 = 2*xo2+xx;
            int n1 = y1*W1_ + x1;
            int cbase = (2*y1)*W0_ + 2*x1;
            float4 a = s[(cbase       )*4 + d4];
            float4 b = s[(cbase+1     )*4 + d4];
            float4 c = s[(cbase+W0_   )*4 + d4];
            float4 d = s[(cbase+W0_+1 )*4 + d4];
            float4 o;
            o.x = 0.25f*(a.x+b.x+c.x+d.x);
            o.y = 0.25f*(a.y+b.y+c.y+d.y);
            o.z = 0.25f*(a.z+b.z+c.z+d.z);
            o.w = 0.25f*(a.w+b.w+c.w+d.w);
            d1[n1*4 + d4] = o;
            l1[yy*2+xx] = o;
        }
    }
    float4 o2;
    o2.x = 0.25f*(l1[0].x+l1[1].x+l1[2].x+l1[3].x);
    o2.y = 0.25f*(l1[0].y+l1[1].y+l1[2].y+l1[3].y);
    o2.z = 0.25f*(l1[0].z+l1[1].z+l1[2].z+l1[3].z);
    o2.w = 0.25f*(l1[0].w+l1[1].w+l1[2].w+l1[3].w);
    int grp = g >> 4, bh = g & 15;
    if (grp == 0)      q2f[(bh*N2 + n2)*4 + d4] = o2;
    else if (grp == 1) k2T[(bh*4 + d4)*N2 + n2] = o2;
    else               v2T[(bh*4 + d4)*N2 + n2] = o2;
}

// threshold-pruned exact top-16 of 576 exp-values (9 per lane), tie-break smaller global index.
__device__ __forceinline__ void top16_sel(const float ev[9], int lane, float* cv, int* cx, int* ip)
{
    // 1. per-lane head
    float head = ev[0];
#pragma unroll
    for(int i=1;i<9;i++) head = fmaxf(head, ev[i]);

    // 2. T = exact 16th-largest head (ballot radix search)
    float T = kth_largest64(head, 16);   // >=16 values are >= T -> top-16 subset of candidates

    // 3. per-lane candidate count + ballot-based exclusive scan (integer-exact)
    int ci = 0;
#pragma unroll
    for(int i=0;i<9;i++) ci += (ev[i] >= T) ? 1 : 0;
    int excl, C;
    scan_counts64(ci, excl, C);          // C >= 16 guaranteed

    // 4. deposit candidates into this wave's LDS region; pad 4 sentinels
    int o = excl;
#pragma unroll
    for(int i=0;i<9;i++){
        if (ev[i] >= T){
            cv[o] = ev[i];
            cx[o] = i*64 + lane;
            o++;
        }
    }
    if (lane < 4){ cv[C+lane] = -1.0f; cx[C+lane] = 0x7fffffff; }
    // in-wave DS ordering: reads below are same-wave, issued after the writes

    // 5. rank each candidate against all candidates (broadcast float4 scans)
    for(int l=lane; l<C; l+=64){
        float mv = cv[l]; int mi = cx[l];
        int rank = 0;
        for(int c=0;c<C;c+=4){
            float4 vv = *(const float4*)(cv + c);
            int4   ii = *(const int4*)(cx + c);
            rank += (vv.x > mv || (vv.x == mv && ii.x < mi)) ? 1 : 0;
            rank += (vv.y > mv || (vv.y == mv && ii.y < mi)) ? 1 : 0;
            rank += (vv.z > mv || (vv.z == mv && ii.z < mi)) ? 1 : 0;
            rank += (vv.w > mv || (vv.w == mv && ii.w < mi)) ? 1 : 0;
        }
        if (rank < 16) ip[rank] = mi;
    }
}

// register ping-pong staging, ONE query per wave: grid doubled (2304 blocks -> full 32
// wave-slots/CU) for latency hiding; query-A arithmetic chain identical to the verified
// 2-query version -> msg2/idx2 bit-identical.
#define LOADK(KB, T9) { int m_=(T9)*64+lane; \
    KB[0]=kT[0*N2+m_]; KB[1]=kT[1*N2+m_]; KB[2]=kT[2*N2+m_]; KB[3]=kT[3*N2+m_]; }
#define LOADV(VB, T9) { int m_=(T9)*64+lane; \
    VB[0]=vT[0*N2+m_]; VB[1]=vT[1*N2+m_]; VB[2]=vT[2*N2+m_]; VB[3]=vT[3*N2+m_]; }
#define STEPK(T9, KB) { float sA=0.f; \
    _Pragma("unroll") \
    for(int dg=0;dg<4;dg++){ float4 kv=KB[dg]; \
      sA += qr[dg*4+0]*kv.x + qr[dg*4+1]*kv.y + qr[dg*4+2]*kv.z + qr[dg*4+3]*kv.w; } \
    sA *= TEMP; \
    ev[T9]=sA; \
    mx = fmaxf(mx, sA); }
#define STEPV(T9, VB) { \
    float eA=expf(ev[T9]-mx); \
    ev[T9]=eA; sum+=eA; \
    _Pragma("unroll") \
    for(int dg=0;dg<4;dg++){ float4 vv=VB[dg]; \
      acc[dg*4+0]+=eA*vv.x; acc[dg*4+1]+=eA*vv.y; acc[dg*4+2]+=eA*vv.z; acc[dg*4+3]+=eA*vv.w; } }

// ---- level-2 full attention + top-16: 1 query/wave, two passes with max-shift, register
// ping-pong double-buffer per pass (k loads overlap score FMAs; v loads overlap exp+PV). ----
__global__ __launch_bounds__(256) void k_attn2(const float* __restrict__ q2, const float* __restrict__ k2,
    const float* __restrict__ v2, float* __restrict__ msg2, int* __restrict__ idx2)
{
    __shared__ __align__(16) float cval[4][580];
    __shared__ __align__(16) int   cidx[4][580];
    const int bh = blockIdx.x;
    const int wv = threadIdx.x>>6, lane = threadIdx.x&63;
    const int q = blockIdx.y*4 + wv;   // one query per wave

    float qr[16];
    {
        const float4* qp = (const float4*)(q2 + (bh*N2 + q)*16);
#pragma unroll
        for(int dq=0;dq<4;dq++){
            float4 va = qp[dq];
            qr[dq*4+0]=va.x; qr[dq*4+1]=va.y; qr[dq*4+2]=va.z; qr[dq*4+3]=va.w;
        }
    }

    const float4* kT = (const float4*)k2 + bh*4*N2;   // [dg][m]
    const float4* vT = (const float4*)v2 + bh*4*N2;

    // ---- pass 1: scores + running max (k ping-pong) ----
    float ev[9];
    float mx = -1e30f;
    {
        float4 ka[4], kb[4];
        LOADK(ka, 0);
#pragma unroll
        for(int t2=0;t2<4;t2++){
            LOADK(kb, 2*t2+1);
            STEPK(2*t2, ka);
            LOADK(ka, 2*t2+2);
            STEPK(2*t2+1, kb);
        }
        STEPK(8, ka);
    }
#pragma unroll
    for(int st=1; st<64; st<<=1){
        mx = fmaxf(mx, __shfl_xor(mx, st));
    }

    // ---- pass 2: exp + PV accumulate (v ping-pong) ----
    float sum=0.f;
    float acc[16];
#pragma unroll
    for(int d=0;d<16;d++) acc[d]=0.f;
    {
        float4 va_[4], vb[4];
        LOADV(va_, 0);
#pragma unroll
        for(int t2=0;t2<4;t2++){
            LOADV(vb, 2*t2+1);
            STEPV(2*t2, va_);
            LOADV(va_, 2*t2+2);
            STEPV(2*t2+1, vb);
        }
        STEPV(8, va_);
    }
#pragma unroll
    for(int st=1; st<64; st<<=1){
        sum += __shfl_xor(sum, st);
    }

    // ---- tree-reduce 16-dim accumulator over 64 lanes ----
    const bool b5 = (lane & 32) != 0;
    const bool b4 = (lane & 16) != 0;
    const bool b3 = (lane & 8) != 0;
    const bool b2 = (lane & 4) != 0;
    float r8[8];
#pragma unroll
    for(int i=0;i<8;i++){
        float snd  = b5 ? acc[i]   : acc[i+8];
        float kept = b5 ? acc[i+8] : acc[i];
        r8[i] = kept + __shfl_xor(snd, 32);
    }
    float r4[4];
#pragma unroll
    for(int i=0;i<4;i++){
        float snd  = b4 ? r8[i]   : r8[i+4];
        float kept = b4 ? r8[i+4] : r8[i];
        r4[i] = kept + __shfl_xor(snd, 16);
    }
    float r2[2];
#pragma unroll
    for(int i=0;i<2;i++){
        float snd  = b3 ? r4[i]   : r4[i+2];
        float kept = b3 ? r4[i+2] : r4[i];
        r2[i] = kept + __shfl_xor(snd, 8);
    }
    {
        float snd  = b2 ? r2[0] : r2[1];
        float kept = b2 ? r2[1] : r2[0];
        r2[0] = kept + __shfl_xor(snd, 4);
    }
    r2[0] += __shfl_xor(r2[0], 2);
    r2[0] += __shfl_xor(r2[0], 1);
    float inv = 1.0f/sum;
    if ((lane&3)==0){
        msg2[(bh*N2+q)*16 + (lane>>2)] = r2[0]*inv;
    }

    // ---- top-16 (per-wave LDS region) ----
    top16_sel(ev, lane, cval[wv], cidx[wv], idx2 + (bh*N2+q)*16);
}

// ---- FUSED refinement: wave owns 1 parent + its 4 children; shared candidate set, no barrier ----
// Selection ranks on raw s (kth ballot), so __expf (message values only) is safe here.
__global__ __launch_bounds__(256) void k_ref10(
    const float* __restrict__ q1, const float* __restrict__ k1, const float* __restrict__ v1,
    const float* __restrict__ q0, const float* __restrict__ k0, const float* __restrict__ v0,
    const float* __restrict__ msg2, const int* __restrict__ idx2, float* __restrict__ msg0)
{
    __shared__ float msg1s[4][16];
    __shared__ int   idx1s[4][8];
    // XCD swizzle: 9216 blocks = 8 x 1152; each XCD owns 2 contiguous bh
    const int bid = (blockIdx.x & 7)*1152 + (blockIdx.x >> 3);
    const int bh = bid / 576, tile = bid - bh*576;
    const int tyy = tile / 24, txx = tile - tyy*24;
    const int py0 = tyy*2, px0 = txx*2;      // 2x2 parent tile origin (level-1 coords)
    const int wv = threadIdx.x>>6, lane = threadIdx.x&63;

    const int ppy = py0 + (wv>>1), ppx = px0 + (wv&1);   // this wave's parent (level-1)

    // ---------- phase 1: ref1 for parent wv ----------
    {
        const int n  = ppy*W1_ + ppx;
        const int par = (ppy>>1)*W2_ + (ppx>>1);
        const int kk = lane>>2, tt = lane&3, dy = tt>>1, dx = tt&1;
        int p = idx2[(bh*N2+par)*16 + kk];
        int ky = p / W2_, kx = p - ky*W2_;
        int child = (2*ky+dy)*W1_ + 2*kx+dx;

        const float* qp = q1 + (bh*N1+n)*16;
        float qr[16];
#pragma unroll
        for(int d=0; d<16; d+=4){
            float4 qq = *(const float4*)(qp+d);
            qr[d]=qq.x; qr[d+1]=qq.y; qr[d+2]=qq.z; qr[d+3]=qq.w;
        }
        const float4* kp = (const float4*)(k1 + (bh*N1+child)*16);
        float s = 0.f;
#pragma unroll
        for(int dq=0;dq<4;dq++){
            float4 kv = kp[dq];
            s += qr[dq*4+0]*kv.x + qr[dq*4+1]*kv.y + qr[dq*4+2]*kv.z + qr[dq*4+3]*kv.w;
        }
        s *= TEMP;

        // top-8 SET selection hoisted before the softmax reduction (VALU/SALU chain overlaps
        // the DS-pipe shuffle trees below).
        float T8 = kth_largest64(s, 8);
        unsigned long long mgt = __ballot(s > T8);
        unsigned long long meq = __ballot(s == T8);
        int ngt = (int)__popcll(mgt);
        int ltg = __builtin_amdgcn_mbcnt_lo((unsigned)mgt, 0);
        ltg = __builtin_amdgcn_mbcnt_hi((unsigned)(mgt>>32), ltg);
        int lte = __builtin_amdgcn_mbcnt_lo((unsigned)meq, 0);
        lte = __builtin_amdgcn_mbcnt_hi((unsigned)(meq>>32), lte);
        int slot = (s > T8) ? ltg : ((s == T8) ? (ngt + lte) : 8);
        if (slot < 8) idx1s[wv][slot] = child;

        float e = __expf(s);
        float sum = e;
#pragma unroll
        for(int st=1; st<64; st<<=1) sum += __shfl_xor(sum, st);

        float acc[16];
        const float4* vp = (const float4*)(v1 + (bh*N1+child)*16);
#pragma unroll
        for(int dq=0;dq<4;dq++){
            float4 vv = vp[dq];
            acc[dq*4+0]=e*vv.x; acc[dq*4+1]=e*vv.y; acc[dq*4+2]=e*vv.z; acc[dq*4+3]=e*vv.w;
        }
        const bool b5 = (lane & 32) != 0;
        float r8[8];
#pragma unroll
        for(int ii=0;ii<8;ii++){
            float snd  = b5 ? acc[ii]   : acc[ii+8];
            float kept = b5 ? acc[ii+8] : acc[ii];
            r8[ii] = kept + __shfl_xor(snd, 32);
        }
        const bool b4 = (lane & 16) != 0;
        float r4[4];
#pragma unroll
        for(int ii=0;ii<4;ii++){
            float snd  = b4 ? r8[ii]   : r8[ii+4];
            float kept = b4 ? r8[ii+4] : r8[ii];
            r4[ii] = kept + __shfl_xor(snd, 16);
        }
        const bool b3 = (lane & 8) != 0;
        float r2[2];
#pragma unroll
        for(int ii=0;ii<2;ii++){
            float snd  = b3 ? r4[ii]   : r4[ii+2];
            float kept = b3 ? r4[ii+2] : r4[ii];
            r2[ii] = kept + __shfl_xor(snd, 8);
        }
        const bool b2 = (lane & 4) != 0;
        {
            float snd  = b2 ? r2[0] : r2[1];
            float kept = b2 ? r2[1] : r2[0];
            r2[0] = kept + __shfl_xor(snd, 4);
        }
        r2[0] += __shfl_xor(r2[0], 2);
        r2[0] += __shfl_xor(r2[0], 1);

        float inv1 = 1.0f/sum;
        if ((lane&3)==0){
            int d = lane>>2;
            msg1s[wv][d] = msg2[(bh*N2+par)*16 + d] + r2[0]*inv1;
        }
    }
    // no __syncthreads: each wave reads only its own msg1s[wv]/idx1s[wv] (in-wave DS order)

    // ---------- phase 2: this parent's 4 children; both query-iterations' reductions interleaved ----------
    const int j = lane & 31, sub = lane >> 5;
    const int kk = j>>2, tt = j&3, dy = tt>>1, dx = tt&1;
    int p = idx1s[wv][kk];
    int ky = p / W1_, kx = p - ky*W1_;
    int child = (2*ky+dy)*W0_ + 2*kx+dx;

    float kr[16];
    {
        const float4* kp = (const float4*)(k0 + (bh*N0+child)*16);
#pragma unroll
        for(int dq=0;dq<4;dq++){
            float4 kv = kp[dq];
            kr[dq*4+0]=kv.x; kr[dq*4+1]=kv.y; kr[dq*4+2]=kv.z; kr[dq*4+3]=kv.w;
        }
    }
    const int cy0 = 2*ppy, cx0 = 2*ppx + sub;
    int nq[2];
    float s_[2];
#pragma unroll
    for(int it=0; it<2; it++){
        nq[it] = (cy0+it)*W0_ + cx0;
        const float* qp = q0 + (bh*N0+nq[it])*16;
        float qr[16];
#pragma unroll
        for(int d=0; d<16; d+=4){
            float4 qq = *(const float4*)(qp+d);
            qr[d]=qq.x; qr[d+1]=qq.y; qr[d+2]=qq.z; qr[d+3]=qq.w;
        }
        float s = 0.f;
#pragma unroll
        for(int dq=0;dq<4;dq++){
            s += qr[dq*4+0]*kr[dq*4+0] + qr[dq*4+1]*kr[dq*4+1]
               + qr[dq*4+2]*kr[dq*4+2] + qr[dq*4+3]*kr[dq*4+3];
        }
        s_[it] = s * TEMP;
    }
    float vr[16];
    {
        const float4* vp = (const float4*)(v0 + (bh*N0+child)*16);
#pragma unroll
        for(int dq=0;dq<4;dq++){
            float4 vv = vp[dq];
            vr[dq*4+0]=vv.x; vr[dq*4+1]=vv.y; vr[dq*4+2]=vv.z; vr[dq*4+3]=vv.w;
        }
    }
    const float m1d = msg1s[wv][j>>1];

    float e0 = __expf(s_[0]);
    float e1 = __expf(s_[1]);
    float sum0 = e0, sum1 = e1;
#pragma unroll
    for(int st=1; st<32; st<<=1){
        sum0 += __shfl_xor(sum0, st);
        sum1 += __shfl_xor(sum1, st);
    }

    float acc0[16], acc1[16];
#pragma unroll
    for(int d=0;d<16;d++){ acc0[d] = e0*vr[d]; acc1[d] = e1*vr[d]; }

    const bool c4 = (j & 16) != 0;
    float p8A[8], p8B[8];
#pragma unroll
    for(int ii=0;ii<8;ii++){
        float sndA  = c4 ? acc0[ii]   : acc0[ii+8];
        float keptA = c4 ? acc0[ii+8] : acc0[ii];
        p8A[ii] = keptA + __shfl_xor(sndA, 16);
        float sndB  = c4 ? acc1[ii]   : acc1[ii+8];
        float keptB = c4 ? acc1[ii+8] : acc1[ii];
        p8B[ii] = keptB + __shfl_xor(sndB, 16);
    }
    const bool c3 = (j & 8) != 0;
    float p4A[4], p4B[4];
#pragma unroll
    for(int ii=0;ii<4;ii++){
        float sndA  = c3 ? p8A[ii]   : p8A[ii+4];
        float keptA = c3 ? p8A[ii+4] : p8A[ii];
        p4A[ii] = keptA + __shfl_xor(sndA, 8);
        float sndB  = c3 ? p8B[ii]   : p8B[ii+4];
        float keptB = c3 ? p8B[ii+4] : p8B[ii];
        p4B[ii] = keptB + __shfl_xor(sndB, 8);
    }
    const bool c2 = (j & 4) != 0;
    float p2A[2], p2B[2];
#pragma unroll
    for(int ii=0;ii<2;ii++){
        float sndA  = c2 ? p4A[ii]   : p4A[ii+2];
        float keptA = c2 ? p4A[ii+2] : p4A[ii];
        p2A[ii] = keptA + __shfl_xor(sndA, 4);
        float sndB  = c2 ? p4B[ii]   : p4B[ii+2];
        float keptB = c2 ? p4B[ii+2] : p4B[ii];
        p2B[ii] = keptB + __shfl_xor(sndB, 4);
    }
    const bool c1 = (j & 2) != 0;
    {
        float sndA  = c1 ? p2A[0] : p2A[1];
        float keptA = c1 ? p2A[1] : p2A[0];
        p2A[0] = keptA + __shfl_xor(sndA, 2);
        float sndB  = c1 ? p2B[0] : p2B[1];
        float keptB = c1 ? p2B[1] : p2B[0];
        p2B[0] = keptB + __shfl_xor(sndB, 2);
    }
    p2A[0] += __shfl_xor(p2A[0], 1);
    p2B[0] += __shfl_xor(p2B[0], 1);

    float inv0 = 1.0f/sum0, inv1 = 1.0f/sum1;
    if ((j&1)==0){
        int d = j>>1;
        int b_ = bh>>3, h = bh&7;
        msg0[(b_*N0+nq[0])*128 + h*16 + d] = m1d + p2A[0]*inv0;
        msg0[(b_*N0+nq[1])*128 + h*16 + d] = m1d + p2B[0]*inv1;
    }
}

// ---------------- output projection GEMM + bias (same staging prefetch as k_proj) ----------------
__global__ __launch_bounds__(256) void k_out(const float* __restrict__ msg0, const float* __restrict__ Wo,
    const float* __restrict__ bo, float* __restrict__ out)
{
    __shared__ __align__(16) float At[16][68];
    __shared__ __align__(16) float Wt[16][132];
    const int t = threadIdx.x;
    const int m0 = blockIdx.x * 64;
    const int tx = t & 15, ty = t >> 4;

    float acc[4][8];
#pragma unroll
    for(int i=0;i<4;i++)
#pragma unroll
        for(int j=0;j<8;j++) acc[i][j]=0.f;

    const int ar = t>>2, akq = (t&3)*4;
    const int wo = t>>1, wkq = (t&1)*8;

    float4 av = *(const float4*)(msg0 + (m0+ar)*128 + akq);
    float4 w0 = *(const float4*)(Wo + wo*128 + wkq);
    float4 w1 = *(const float4*)(Wo + wo*128 + wkq + 4);

    for(int kc=0;kc<128;kc+=16){
        At[akq+0][ar] = av.x;
        At[akq+1][ar] = av.y;
        At[akq+2][ar] = av.z;
        At[akq+3][ar] = av.w;
        Wt[wkq+0][wo] = w0.x; Wt[wkq+1][wo] = w0.y;
        Wt[wkq+2][wo] = w0.z; Wt[wkq+3][wo] = w0.w;
        Wt[wkq+4][wo] = w1.x; Wt[wkq+5][wo] = w1.y;
        Wt[wkq+6][wo] = w1.z; Wt[wkq+7][wo] = w1.w;
        __syncthreads();
        float4 nav, nw0, nw1;
        if (kc < 112){
            nav = *(const float4*)(msg0 + (m0+ar)*128 + kc+16 + akq);
            nw0 = *(const float4*)(Wo + wo*128 + kc+16 + wkq);
            nw1 = *(const float4*)(Wo + wo*128 + kc+16 + wkq + 4);
        }
#pragma unroll
        for(int kk=0;kk<16;kk++){
            float4 a4 = *(const float4*)&At[kk][ty*4];
            float4 wa = *(const float4*)&Wt[kk][tx*4];
            float4 wb = *(const float4*)&Wt[kk][64 + tx*4];
            float avr[4] = {a4.x,a4.y,a4.z,a4.w};
            float wvr[8] = {wa.x,wa.y,wa.z,wa.w, wb.x,wb.y,wb.z,wb.w};
#pragma unroll
            for(int i=0;i<4;i++)
#pragma unroll
                for(int j=0;j<8;j++) acc[i][j] += avr[i]*wvr[j];
        }
        __syncthreads();
        if (kc < 112){ av = nav; w0 = nw0; w1 = nw1; }
    }
#pragma unroll
    for(int i=0;i<4;i++){
        int m = m0 + ty*4 + i;
        float4 sA = make_float4(acc[i][0]+bo[tx*4+0], acc[i][1]+bo[tx*4+1],
                                acc[i][2]+bo[tx*4+2], acc[i][3]+bo[tx*4+3]);
        float4 sB = make_float4(acc[i][4]+bo[64+tx*4+0], acc[i][5]+bo[64+tx*4+1],
                                acc[i][6]+bo[64+tx*4+2], acc[i][7]+bo[64+tx*4+3]);
        *(float4*)(out + m*128 + tx*4)      = sA;
        *(float4*)(out + m*128 + 64 + tx*4) = sB;
    }
}

extern "C" void kernel_launch(void* const* d_in, const int* in_sizes, int n_in,
                              void* d_out, int out_size, void* d_ws, size_t ws_size,
                              hipStream_t stream) {
    const float* x  = (const float*)d_in[0];
    const float* tg = (const float*)d_in[1];
    const float* Wq = (const float*)d_in[2];
    const float* Wk = (const float*)d_in[3];
    const float* Wv = (const float*)d_in[4];
    const float* Wo = (const float*)d_in[5];
    const float* bo = (const float*)d_in[6];

    float* ws = (float*)d_ws;
    float* q0   = ws + 0;
    float* k0   = ws + 2359296;
    float* v0   = ws + 4718592;
    float* q1   = ws + 7077888;
    float* k1   = ws + 7667712;
    float* v1   = ws + 8257536;
    float* q2   = ws + 8847360;
    float* k2   = ws + 8994816;   // k2T [bh][dg][m] float4
    float* v2   = ws + 9142272;   // v2T
    float* msg2 = ws + 9289728;
    float* msg0 = ws + 10027008;
    int*   idx2 = (int*)(ws + 12386304);

    k_proj<<<dim3(288,3), 256, 0, stream>>>(x, tg, Wq, Wk, Wv, q0, k0, v0);
    k_pool01<<<432, 256, 0, stream>>>((const float4*)q0, (float4*)q1,
                                      (float4*)q2, (float4*)k2, (float4*)v2);
    k_attn2<<<dim3(16,144), 256, 0, stream>>>(q2, k2, v2, msg2, idx2);
    k_ref10<<<9216, 256, 0, stream>>>(q1, k1, v1, q0, k0, v0, msg2, idx2, msg0);
    k_out<<<288, 256, 0, stream>>>(msg0, Wo, bo, (float*)d_out);
}